// Round 1
// baseline (407.461 us; speedup 1.0000x reference)
//
#include <hip/hip_runtime.h>
#include <math.h>

#define S_LEN 2048
#define DM 1024

typedef __attribute__((ext_vector_type(8))) __bf16 bf16x8;
typedef __attribute__((ext_vector_type(4))) float floatx4;

typedef __attribute__((address_space(1))) const unsigned int g_u32;
typedef __attribute__((address_space(3))) unsigned int l_u32;

__device__ __forceinline__ unsigned short f2bf(float f) {
  union { float f; unsigned int u; } v; v.f = f;
  return (unsigned short)((v.u + 0x7fffu + ((v.u >> 16) & 1u)) >> 16);
}
__device__ __forceinline__ float bf2f(unsigned short u) {
  union { unsigned int u; float f; } v; v.u = ((unsigned int)u) << 16;
  return v.f;
}
__device__ __forceinline__ bf16x8 ld_frag(const unsigned short* p) {
  union { uint4 u; bf16x8 v; } t;
  t.u = *(const uint4*)p;
  return t.v;
}

// ---------------- dtype probe: 1 = buffers are fp32, 0 = bf16 ----------------
__global__ void detect_k(const unsigned short* __restrict__ x, int* __restrict__ flag) {
  __shared__ int cnt;
  if (threadIdx.x == 0) cnt = 0;
  __syncthreads();
  int local = 0;
  for (int i = threadIdx.x; i < 4096; i += 256) {
    unsigned short u = x[i];
    int e = (u >> 7) & 0xFF;
    if (e > 140) local++;
  }
  atomicAdd(&cnt, local);
  __syncthreads();
  if (threadIdx.x == 0) *flag = (cnt > 64) ? 1 : 0;
}

// ---------------- convert hidden_states to bf16 (8 elems/thread) ----------------
__global__ void conv_x(const void* __restrict__ src, unsigned short* __restrict__ dst,
                       const int* __restrict__ flag, int n8) {
  int i = blockIdx.x * 256 + threadIdx.x;
  if (i >= n8) return;
  if (*flag) {
    const float4* s = (const float4*)src;
    float4 a = s[2 * i], b = s[2 * i + 1];
    union { uint4 u4; unsigned short s[8]; } o;
    o.s[0] = f2bf(a.x); o.s[1] = f2bf(a.y); o.s[2] = f2bf(a.z); o.s[3] = f2bf(a.w);
    o.s[4] = f2bf(b.x); o.s[5] = f2bf(b.y); o.s[6] = f2bf(b.z); o.s[7] = f2bf(b.w);
    ((uint4*)dst)[i] = o.u4;
  } else {
    ((uint4*)dst)[i] = ((const uint4*)src)[i];
  }
}

// ---------------- transpose 1024x1024 weights -> bf16 W^T (4 mats, one launch) ----------------
__global__ void transpose_w(const void* __restrict__ s0, const void* __restrict__ s1,
                            const void* __restrict__ s2, const void* __restrict__ s3,
                            unsigned short* __restrict__ Wcat, unsigned short* __restrict__ Wto,
                            const int* __restrict__ flag) {
  __shared__ float tile[32][33];
  const int z = blockIdx.z;
  const void* src = (z == 0) ? s0 : (z == 1) ? s1 : (z == 2) ? s2 : s3;
  unsigned short* dst = (z < 3) ? (Wcat + (size_t)z * 1048576) : Wto;
  const int isf = *flag;
  int x = blockIdx.x * 32 + threadIdx.x;
  int y0 = blockIdx.y * 32;
  for (int i = threadIdx.y; i < 32; i += 8) {
    float v;
    if (isf) v = ((const float*)src)[(size_t)(y0 + i) * DM + x];
    else     v = bf2f(((const unsigned short*)src)[(size_t)(y0 + i) * DM + x]);
    tile[i][threadIdx.x] = v;
  }
  __syncthreads();
  int xo = y0 + threadIdx.x;
  for (int i = threadIdx.y; i < 32; i += 8)
    dst[(size_t)(blockIdx.x * 32 + i) * DM + xo] = f2bf(tile[threadIdx.x][i]);
}

// ---------------- dense relative-position bias table [16][4095] ----------------
__global__ void bias_k(const void* __restrict__ table, float* __restrict__ out,
                       const int* __restrict__ flag) {
  int idx = blockIdx.x * 256 + threadIdx.x;
  if (idx >= 16 * 4095) return;
  int h = idx / 4095;
  int j = idx - h * 4095;
  int delta = j - 2047;            // k - q
  int bucket = (delta > 0) ? 16 : 0;
  int ad = (delta < 0) ? -delta : delta;
  int smallv;
  if (ad < 8) smallv = ad;
  else {
    int l = (int)(log((double)ad * 0.125) * (8.0 / log(16.0)));
    smallv = 8 + l;
    if (smallv > 15) smallv = 15;
  }
  bucket += smallv;
  float v;
  if (*flag) v = ((const float*)table)[bucket * 16 + h];
  else       v = bf2f(((const unsigned short*)table)[bucket * 16 + h]);
  out[idx] = v;
}

// ---------------- bf16 GEMM, m97-style (global_load_lds, unpadded LDS) ----------------
// mode 0: fused QKV, N=3072, C = Qb base (Q|K|V contiguous, V transposed)
__global__ __launch_bounds__(256) void gemm_bt(
    const unsigned short* __restrict__ A, const unsigned short* __restrict__ Bt,
    void* __restrict__ C, int mode, const int* __restrict__ flag)
{
  __shared__ __align__(16) unsigned short As[128 * 64];
  __shared__ __align__(16) unsigned short Bs[128 * 64];
  const int tid = threadIdx.x;
  const int lane = tid & 63, wave = tid >> 6;
  const int l16 = lane & 15, quad = lane >> 4;
  const int wm = (wave >> 1) << 6, wn = (wave & 1) << 6;
  const int m0 = blockIdx.y << 7, n0 = blockIdx.x << 7;
  const int lrow = lane >> 3, lcol = (lane & 7) << 3;

  floatx4 acc[4][4] = {};

  for (int k0 = 0; k0 < 1024; k0 += 64) {
    __syncthreads();
#pragma unroll
    for (int i = 0; i < 4; ++i) {
      int r0 = wave * 32 + i * 8;
      __builtin_amdgcn_global_load_lds(
          (g_u32*)(const void*)(A + (size_t)(m0 + r0 + lrow) * 1024 + k0 + lcol),
          (l_u32*)(void*)&As[r0 * 64], 16, 0, 0);
      __builtin_amdgcn_global_load_lds(
          (g_u32*)(const void*)(Bt + (size_t)(n0 + r0 + lrow) * 1024 + k0 + lcol),
          (l_u32*)(void*)&Bs[r0 * 64], 16, 0, 0);
    }
    __syncthreads();
#pragma unroll
    for (int ks = 0; ks < 2; ++ks) {
      bf16x8 a[4], b[4];
#pragma unroll
      for (int mi = 0; mi < 4; ++mi)
        a[mi] = *(const bf16x8*)&As[(wm + mi * 16 + l16) * 64 + ks * 32 + quad * 8];
#pragma unroll
      for (int ni = 0; ni < 4; ++ni)
        b[ni] = *(const bf16x8*)&Bs[(wn + ni * 16 + l16) * 64 + ks * 32 + quad * 8];
#pragma unroll
      for (int mi = 0; mi < 4; ++mi)
#pragma unroll
        for (int ni = 0; ni < 4; ++ni)
          acc[mi][ni] = __builtin_amdgcn_mfma_f32_16x16x32_bf16(a[mi], b[ni], acc[mi][ni], 0, 0, 0);
    }
  }

  if (mode == 0) {
    unsigned short* Cs = (unsigned short*)C;
    const int mat = n0 >> 10;           // uniform per block
#pragma unroll
    for (int mi = 0; mi < 4; ++mi)
#pragma unroll
      for (int ni = 0; ni < 4; ++ni)
#pragma unroll
        for (int i = 0; i < 4; ++i) {
          int m = m0 + wm + mi * 16 + quad * 4 + i;
          int n = (n0 & 1023) + wn + ni * 16 + l16;
          int b = m >> 11, s = m & 2047, h = n >> 6, d = n & 63;
          unsigned short v = f2bf(acc[mi][ni][i]);
          if (mat < 2)
            Cs[(size_t)mat * 4194304 + (((size_t)(b * 16 + h)) * 2048 + s) * 64 + d] = v;
          else
            Cs[(size_t)2 * 4194304 + (((size_t)(b * 16 + h)) * 64 + d) * 2048 + s] = v;
        }
  } else {
    const int isf = *flag;
#pragma unroll
    for (int mi = 0; mi < 4; ++mi)
#pragma unroll
      for (int ni = 0; ni < 4; ++ni)
#pragma unroll
        for (int i = 0; i < 4; ++i) {
          int m = m0 + wm + mi * 16 + quad * 4 + i;
          int n = n0 + wn + ni * 16 + l16;
          size_t idx = (size_t)m * 1024 + n;
          float v = acc[mi][ni][i];
          if (isf) ((float*)C)[idx] = v;
          else     ((unsigned short*)C)[idx] = f2bf(v);
        }
  }
}

// ---------------- out GEMM, 128x64 tiles (512 blocks = 2/CU) ----------------
__global__ __launch_bounds__(256) void gemm_out(
    const unsigned short* __restrict__ A, const unsigned short* __restrict__ Bt,
    void* __restrict__ C, const int* __restrict__ flag)
{
  __shared__ __align__(16) unsigned short As[128 * 64];
  __shared__ __align__(16) unsigned short Bs[64 * 64];
  const int tid = threadIdx.x;
  const int lane = tid & 63, wave = tid >> 6;
  const int l16 = lane & 15, quad = lane >> 4;
  const int wm = (wave >> 1) << 6, wn = (wave & 1) << 5;
  const int m0 = blockIdx.y << 7, n0 = blockIdx.x << 6;
  const int lrow = lane >> 3, lcol = (lane & 7) << 3;

  floatx4 acc[4][2] = {};

  for (int k0 = 0; k0 < 1024; k0 += 64) {
    __syncthreads();
#pragma unroll
    for (int i = 0; i < 4; ++i) {
      int r0 = wave * 32 + i * 8;
      __builtin_amdgcn_global_load_lds(
          (g_u32*)(const void*)(A + (size_t)(m0 + r0 + lrow) * 1024 + k0 + lcol),
          (l_u32*)(void*)&As[r0 * 64], 16, 0, 0);
    }
#pragma unroll
    for (int i = 0; i < 2; ++i) {
      int r0 = wave * 16 + i * 8;
      __builtin_amdgcn_global_load_lds(
          (g_u32*)(const void*)(Bt + (size_t)(n0 + r0 + lrow) * 1024 + k0 + lcol),
          (l_u32*)(void*)&Bs[r0 * 64], 16, 0, 0);
    }
    __syncthreads();
#pragma unroll
    for (int ks = 0; ks < 2; ++ks) {
      bf16x8 a[4], b[2];
#pragma unroll
      for (int mi = 0; mi < 4; ++mi)
        a[mi] = *(const bf16x8*)&As[(wm + mi * 16 + l16) * 64 + ks * 32 + quad * 8];
#pragma unroll
      for (int ni = 0; ni < 2; ++ni)
        b[ni] = *(const bf16x8*)&Bs[(wn + ni * 16 + l16) * 64 + ks * 32 + quad * 8];
#pragma unroll
      for (int mi = 0; mi < 4; ++mi)
#pragma unroll
        for (int ni = 0; ni < 2; ++ni)
          acc[mi][ni] = __builtin_amdgcn_mfma_f32_16x16x32_bf16(a[mi], b[ni], acc[mi][ni], 0, 0, 0);
    }
  }

  const int isf = *flag;
#pragma unroll
  for (int mi = 0; mi < 4; ++mi)
#pragma unroll
    for (int ni = 0; ni < 2; ++ni)
#pragma unroll
      for (int i = 0; i < 4; ++i) {
        int m = m0 + wm + mi * 16 + quad * 4 + i;
        int n = n0 + wn + ni * 16 + l16;
        size_t idx = (size_t)m * 1024 + n;
        float v = acc[mi][ni][i];
        if (isf) ((float*)C)[idx] = v;
        else     ((unsigned short*)C)[idx] = f2bf(v);
      }
}

// ---------------- flash attention: Q-tile 64 (16 rows/wave), fixed-max softmax ----------------
// grid (32 q-blocks, 32 bh), block 256 -> 1024 blocks = 4 blocks/CU = 4 waves/SIMD
// (was 512 blocks = 2 waves/SIMD, the occupancy cap that left MfmaUtil at 10%).
// Bias table shrunk to the 2111-entry window a 64-row q-block can address so
// LDS stays at 25.9 KB/block (4 blocks/CU fits in 104 KB).
__global__ __launch_bounds__(256) void attn_k(
    const unsigned short* __restrict__ Q, const unsigned short* __restrict__ K,
    const unsigned short* __restrict__ Vt, const float* __restrict__ bias,
    unsigned short* __restrict__ ctx)
{
  __shared__ __align__(16) unsigned short Ps[4][16][136];  // wave-private, padded (+8) rows
  __shared__ float Bls[2112];   // windowed bias*log2e - 24: entry i = delta idx (i + 1984 - q0)
  const int tid = threadIdx.x;
  const int lane = tid & 63, wave = tid >> 6;
  const int l16 = lane & 15, quad = lane >> 4;
  const int bh = blockIdx.y;
  const int b = bh >> 4, h = bh & 15;
  const int q0 = blockIdx.x << 6;
  const int wq = wave << 4;

  const unsigned short* Qp = Q + (size_t)bh * S_LEN * 64;
  const unsigned short* Kp = K + (size_t)bh * S_LEN * 64;
  const unsigned short* Vp = Vt + (size_t)bh * 64 * S_LEN;
  const float* biasg = bias + h * 4095 + (1984 - q0);

  // stage pre-scaled bias window; indices i+1984-q0 span [0,4094] for all q0 -> no guard
  for (int i = tid; i < 2111; i += 256)
    Bls[i] = fmaf(biasg[i], 1.44269504f, -24.f);
  __syncthreads();

  bf16x8 qf[2];
#pragma unroll
  for (int ks = 0; ks < 2; ++ks)
    qf[ks] = ld_frag(Qp + (size_t)(q0 + wq + l16) * 64 + ks * 32 + quad * 8);

  float l_run[4] = {};
  floatx4 oacc[4] = {};

  const int rbase = 63 + l16 - wq - quad * 4;  // local bias base minus kv0 and i

  for (int kv0 = 0; kv0 < S_LEN; kv0 += 128) {
    floatx4 sac[8] = {};
#pragma unroll
    for (int ks = 0; ks < 2; ++ks) {
      bf16x8 kf[8];
#pragma unroll
      for (int ni = 0; ni < 8; ++ni)
        kf[ni] = ld_frag(Kp + (size_t)(kv0 + ni * 16 + l16) * 64 + ks * 32 + quad * 8);
#pragma unroll
      for (int ni = 0; ni < 8; ++ni)
        sac[ni] = __builtin_amdgcn_mfma_f32_16x16x32_bf16(qf[ks], kf[ni], sac[ni], 0, 0, 0);
    }

    // fixed-max softmax: e = 2^(s*log2e + Bls); lane-local partial row sums
#pragma unroll
    for (int i = 0; i < 4; ++i) {
      const int bbase = kv0 + rbase - i;
      float sum = 0.f;
#pragma unroll
      for (int ni = 0; ni < 8; ++ni) {
        float e = __builtin_amdgcn_exp2f(
            fmaf(sac[ni][i], 1.44269504f, Bls[bbase + ni * 16]));
        sac[ni][i] = e;
        sum += e;
      }
      l_run[i] += sum;
    }

    // P (C/D layout) -> LDS -> A-operand layout, wave-private (no barrier needed)
#pragma unroll
    for (int ni = 0; ni < 8; ++ni)
#pragma unroll
      for (int i = 0; i < 4; ++i)
        Ps[wave][quad * 4 + i][ni * 16 + l16] = f2bf(sac[ni][i]);

#pragma unroll
    for (int ks2 = 0; ks2 < 4; ++ks2) {
      bf16x8 af, vf[4];
      af = *(const bf16x8*)&Ps[wave][l16][ks2 * 32 + quad * 8];
#pragma unroll
      for (int ni = 0; ni < 4; ++ni)
        vf[ni] = ld_frag(Vp + (size_t)(ni * 16 + l16) * S_LEN + kv0 + ks2 * 32 + quad * 8);
#pragma unroll
      for (int ni = 0; ni < 4; ++ni)
        oacc[ni] = __builtin_amdgcn_mfma_f32_16x16x32_bf16(af, vf[ni], oacc[ni], 0, 0, 0);
    }
  }

  // one-time cross-lane l reduction (columns live on the 16 lanes of each quad)
  float linv[4];
#pragma unroll
  for (int i = 0; i < 4; ++i) {
    float ls = l_run[i];
    ls += __shfl_xor(ls, 1);
    ls += __shfl_xor(ls, 2);
    ls += __shfl_xor(ls, 4);
    ls += __shfl_xor(ls, 8);
    linv[i] = 1.f / ls;
  }

#pragma unroll
  for (int ni = 0; ni < 4; ++ni)
#pragma unroll
    for (int i = 0; i < 4; ++i) {
      float v = oacc[ni][i] * linv[i];
      int srow = q0 + wq + quad * 4 + i;
      ctx[((size_t)(b * 2048 + srow)) * 1024 + h * 64 + ni * 16 + l16] = f2bf(v);
    }
}

extern "C" void kernel_launch(void* const* d_in, const int* in_sizes, int n_in,
                              void* d_out, int out_size, void* d_ws, size_t ws_size,
                              hipStream_t stream) {
  char* ws = (char*)d_ws;
  // R2/R6-proven workspace layout, byte-for-byte.
  unsigned short* Xbf  = (unsigned short*)(ws);                    // 8 MB
  unsigned short* Wcat = (unsigned short*)(ws + 8388608);          // 6 MB (Wq^T|Wk^T|Wv^T)
  unsigned short* Wto  = (unsigned short*)(ws + 14680064);         // 2 MB
  unsigned short* Qb   = (unsigned short*)(ws + 16777216);         // 8 MB  (K at +8MB, Vt at +16MB)
  unsigned short* ctx  = (unsigned short*)(ws + 41943040);         // 8 MB
  float*          bias = (float*)(ws + 50331648);                  // 16*4095*4
  int*            flag = (int*)(ws + 50593792);

  unsigned short* Kb  = Qb + 4194304;
  unsigned short* Vtb = Qb + 8388608;

  detect_k<<<1, 256, 0, stream>>>((const unsigned short*)d_in[0], flag);
  conv_x<<<2048, 256, 0, stream>>>(d_in[0], Xbf, flag, 524288);
  transpose_w<<<dim3(32, 32, 4), dim3(32, 8), 0, stream>>>(
      d_in[1], d_in[2], d_in[3], d_in[4], Wcat, Wto, flag);
  bias_k<<<256, 256, 0, stream>>>(d_in[5], bias, flag);

  // fused QKV GEMM: [4096,1024] @ [3072,1024]^T -> Q|K|Vt
  gemm_bt<<<dim3(24, 32), 256, 0, stream>>>(Xbf, Wcat, Qb, 0, flag);

  // flash attention: Q-tile 64, 1024 blocks (4/CU)
  attn_k<<<dim3(32, 32), 256, 0, stream>>>(Qb, Kb, Vtb, bias, ctx);

  // out GEMM: [4096,1024] @ [1024,1024]^T, 128x64 tiles
  gemm_out<<<dim3(16, 32), 256, 0, stream>>>(ctx, Wto, d_out, flag);
}

// Round 2
// 406.318 us; speedup vs baseline: 1.0028x; 1.0028x over previous
//
#include <hip/hip_runtime.h>
#include <math.h>

#define S_LEN 2048
#define DM 1024

typedef __attribute__((ext_vector_type(8))) __bf16 bf16x8;
typedef __attribute__((ext_vector_type(4))) float floatx4;

typedef __attribute__((address_space(1))) const unsigned int g_u32;
typedef __attribute__((address_space(3))) unsigned int l_u32;

__device__ __forceinline__ unsigned short f2bf(float f) {
  union { float f; unsigned int u; } v; v.f = f;
  return (unsigned short)((v.u + 0x7fffu + ((v.u >> 16) & 1u)) >> 16);
}
__device__ __forceinline__ float bf2f(unsigned short u) {
  union { unsigned int u; float f; } v; v.u = ((unsigned int)u) << 16;
  return v.f;
}
__device__ __forceinline__ bf16x8 ld_frag(const unsigned short* p) {
  union { uint4 u; bf16x8 v; } t;
  t.u = *(const uint4*)p;
  return t.v;
}

// ---------------- dtype probe: 1 = buffers are fp32, 0 = bf16 ----------------
__global__ void detect_k(const unsigned short* __restrict__ x, int* __restrict__ flag) {
  __shared__ int cnt;
  if (threadIdx.x == 0) cnt = 0;
  __syncthreads();
  int local = 0;
  for (int i = threadIdx.x; i < 4096; i += 256) {
    unsigned short u = x[i];
    int e = (u >> 7) & 0xFF;
    if (e > 140) local++;
  }
  atomicAdd(&cnt, local);
  __syncthreads();
  if (threadIdx.x == 0) *flag = (cnt > 64) ? 1 : 0;
}

// ---------------- convert hidden_states to bf16 (8 elems/thread) ----------------
__global__ void conv_x(const void* __restrict__ src, unsigned short* __restrict__ dst,
                       const int* __restrict__ flag, int n8) {
  int i = blockIdx.x * 256 + threadIdx.x;
  if (i >= n8) return;
  if (*flag) {
    const float4* s = (const float4*)src;
    float4 a = s[2 * i], b = s[2 * i + 1];
    union { uint4 u4; unsigned short s[8]; } o;
    o.s[0] = f2bf(a.x); o.s[1] = f2bf(a.y); o.s[2] = f2bf(a.z); o.s[3] = f2bf(a.w);
    o.s[4] = f2bf(b.x); o.s[5] = f2bf(b.y); o.s[6] = f2bf(b.z); o.s[7] = f2bf(b.w);
    ((uint4*)dst)[i] = o.u4;
  } else {
    ((uint4*)dst)[i] = ((const uint4*)src)[i];
  }
}

// ---------------- transpose 1024x1024 weights -> bf16 W^T (4 mats, one launch) ----------------
__global__ void transpose_w(const void* __restrict__ s0, const void* __restrict__ s1,
                            const void* __restrict__ s2, const void* __restrict__ s3,
                            unsigned short* __restrict__ Wcat, unsigned short* __restrict__ Wto,
                            const int* __restrict__ flag) {
  __shared__ float tile[32][33];
  const int z = blockIdx.z;
  const void* src = (z == 0) ? s0 : (z == 1) ? s1 : (z == 2) ? s2 : s3;
  unsigned short* dst = (z < 3) ? (Wcat + (size_t)z * 1048576) : Wto;
  const int isf = *flag;
  int x = blockIdx.x * 32 + threadIdx.x;
  int y0 = blockIdx.y * 32;
  for (int i = threadIdx.y; i < 32; i += 8) {
    float v;
    if (isf) v = ((const float*)src)[(size_t)(y0 + i) * DM + x];
    else     v = bf2f(((const unsigned short*)src)[(size_t)(y0 + i) * DM + x]);
    tile[i][threadIdx.x] = v;
  }
  __syncthreads();
  int xo = y0 + threadIdx.x;
  for (int i = threadIdx.y; i < 32; i += 8)
    dst[(size_t)(blockIdx.x * 32 + i) * DM + xo] = f2bf(tile[threadIdx.x][i]);
}

// ---------------- dense relative-position bias table [16][4095] ----------------
__global__ void bias_k(const void* __restrict__ table, float* __restrict__ out,
                       const int* __restrict__ flag) {
  int idx = blockIdx.x * 256 + threadIdx.x;
  if (idx >= 16 * 4095) return;
  int h = idx / 4095;
  int j = idx - h * 4095;
  int delta = j - 2047;            // k - q
  int bucket = (delta > 0) ? 16 : 0;
  int ad = (delta < 0) ? -delta : delta;
  int smallv;
  if (ad < 8) smallv = ad;
  else {
    int l = (int)(log((double)ad * 0.125) * (8.0 / log(16.0)));
    smallv = 8 + l;
    if (smallv > 15) smallv = 15;
  }
  bucket += smallv;
  float v;
  if (*flag) v = ((const float*)table)[bucket * 16 + h];
  else       v = bf2f(((const unsigned short*)table)[bucket * 16 + h]);
  out[idx] = v;
}

// ---------------- bf16 GEMM, m97-style (global_load_lds, unpadded LDS) ----------------
// mode 0: fused QKV, N=3072, C = Qb base (Q|K|V contiguous, V transposed)
__global__ __launch_bounds__(256) void gemm_bt(
    const unsigned short* __restrict__ A, const unsigned short* __restrict__ Bt,
    void* __restrict__ C, int mode, const int* __restrict__ flag)
{
  __shared__ __align__(16) unsigned short As[128 * 64];
  __shared__ __align__(16) unsigned short Bs[128 * 64];
  const int tid = threadIdx.x;
  const int lane = tid & 63, wave = tid >> 6;
  const int l16 = lane & 15, quad = lane >> 4;
  const int wm = (wave >> 1) << 6, wn = (wave & 1) << 6;
  const int m0 = blockIdx.y << 7, n0 = blockIdx.x << 7;
  const int lrow = lane >> 3, lcol = (lane & 7) << 3;

  floatx4 acc[4][4] = {};

  for (int k0 = 0; k0 < 1024; k0 += 64) {
    __syncthreads();
#pragma unroll
    for (int i = 0; i < 4; ++i) {
      int r0 = wave * 32 + i * 8;
      __builtin_amdgcn_global_load_lds(
          (g_u32*)(const void*)(A + (size_t)(m0 + r0 + lrow) * 1024 + k0 + lcol),
          (l_u32*)(void*)&As[r0 * 64], 16, 0, 0);
      __builtin_amdgcn_global_load_lds(
          (g_u32*)(const void*)(Bt + (size_t)(n0 + r0 + lrow) * 1024 + k0 + lcol),
          (l_u32*)(void*)&Bs[r0 * 64], 16, 0, 0);
    }
    __syncthreads();
#pragma unroll
    for (int ks = 0; ks < 2; ++ks) {
      bf16x8 a[4], b[4];
#pragma unroll
      for (int mi = 0; mi < 4; ++mi)
        a[mi] = *(const bf16x8*)&As[(wm + mi * 16 + l16) * 64 + ks * 32 + quad * 8];
#pragma unroll
      for (int ni = 0; ni < 4; ++ni)
        b[ni] = *(const bf16x8*)&Bs[(wn + ni * 16 + l16) * 64 + ks * 32 + quad * 8];
#pragma unroll
      for (int mi = 0; mi < 4; ++mi)
#pragma unroll
        for (int ni = 0; ni < 4; ++ni)
          acc[mi][ni] = __builtin_amdgcn_mfma_f32_16x16x32_bf16(a[mi], b[ni], acc[mi][ni], 0, 0, 0);
    }
  }

  if (mode == 0) {
    unsigned short* Cs = (unsigned short*)C;
    const int mat = n0 >> 10;           // uniform per block
#pragma unroll
    for (int mi = 0; mi < 4; ++mi)
#pragma unroll
      for (int ni = 0; ni < 4; ++ni)
#pragma unroll
        for (int i = 0; i < 4; ++i) {
          int m = m0 + wm + mi * 16 + quad * 4 + i;
          int n = (n0 & 1023) + wn + ni * 16 + l16;
          int b = m >> 11, s = m & 2047, h = n >> 6, d = n & 63;
          unsigned short v = f2bf(acc[mi][ni][i]);
          if (mat < 2)
            Cs[(size_t)mat * 4194304 + (((size_t)(b * 16 + h)) * 2048 + s) * 64 + d] = v;
          else
            Cs[(size_t)2 * 4194304 + (((size_t)(b * 16 + h)) * 64 + d) * 2048 + s] = v;
        }
  } else {
    const int isf = *flag;
#pragma unroll
    for (int mi = 0; mi < 4; ++mi)
#pragma unroll
      for (int ni = 0; ni < 4; ++ni)
#pragma unroll
        for (int i = 0; i < 4; ++i) {
          int m = m0 + wm + mi * 16 + quad * 4 + i;
          int n = n0 + wn + ni * 16 + l16;
          size_t idx = (size_t)m * 1024 + n;
          float v = acc[mi][ni][i];
          if (isf) ((float*)C)[idx] = v;
          else     ((unsigned short*)C)[idx] = f2bf(v);
        }
  }
}

// ---------------- out GEMM, 128x64 tiles (512 blocks = 2/CU) ----------------
__global__ __launch_bounds__(256) void gemm_out(
    const unsigned short* __restrict__ A, const unsigned short* __restrict__ Bt,
    void* __restrict__ C, const int* __restrict__ flag)
{
  __shared__ __align__(16) unsigned short As[128 * 64];
  __shared__ __align__(16) unsigned short Bs[64 * 64];
  const int tid = threadIdx.x;
  const int lane = tid & 63, wave = tid >> 6;
  const int l16 = lane & 15, quad = lane >> 4;
  const int wm = (wave >> 1) << 6, wn = (wave & 1) << 5;
  const int m0 = blockIdx.y << 7, n0 = blockIdx.x << 6;
  const int lrow = lane >> 3, lcol = (lane & 7) << 3;

  floatx4 acc[4][2] = {};

  for (int k0 = 0; k0 < 1024; k0 += 64) {
    __syncthreads();
#pragma unroll
    for (int i = 0; i < 4; ++i) {
      int r0 = wave * 32 + i * 8;
      __builtin_amdgcn_global_load_lds(
          (g_u32*)(const void*)(A + (size_t)(m0 + r0 + lrow) * 1024 + k0 + lcol),
          (l_u32*)(void*)&As[r0 * 64], 16, 0, 0);
    }
#pragma unroll
    for (int i = 0; i < 2; ++i) {
      int r0 = wave * 16 + i * 8;
      __builtin_amdgcn_global_load_lds(
          (g_u32*)(const void*)(Bt + (size_t)(n0 + r0 + lrow) * 1024 + k0 + lcol),
          (l_u32*)(void*)&Bs[r0 * 64], 16, 0, 0);
    }
    __syncthreads();
#pragma unroll
    for (int ks = 0; ks < 2; ++ks) {
      bf16x8 a[4], b[2];
#pragma unroll
      for (int mi = 0; mi < 4; ++mi)
        a[mi] = *(const bf16x8*)&As[(wm + mi * 16 + l16) * 64 + ks * 32 + quad * 8];
#pragma unroll
      for (int ni = 0; ni < 2; ++ni)
        b[ni] = *(const bf16x8*)&Bs[(wn + ni * 16 + l16) * 64 + ks * 32 + quad * 8];
#pragma unroll
      for (int mi = 0; mi < 4; ++mi)
#pragma unroll
        for (int ni = 0; ni < 2; ++ni)
          acc[mi][ni] = __builtin_amdgcn_mfma_f32_16x16x32_bf16(a[mi], b[ni], acc[mi][ni], 0, 0, 0);
    }
  }

  const int isf = *flag;
#pragma unroll
  for (int mi = 0; mi < 4; ++mi)
#pragma unroll
    for (int ni = 0; ni < 2; ++ni)
#pragma unroll
      for (int i = 0; i < 4; ++i) {
        int m = m0 + wm + mi * 16 + quad * 4 + i;
        int n = n0 + wn + ni * 16 + l16;
        size_t idx = (size_t)m * 1024 + n;
        float v = acc[mi][ni][i];
        if (isf) ((float*)C)[idx] = v;
        else     ((unsigned short*)C)[idx] = f2bf(v);
      }
}

// ---------------- flash attention: Q-tile 128, 8 waves x 16 q-rows, 512 thr ----------------
// grid (16,32) = 512 blocks -> 2 blocks/CU -> 16 waves/CU -> 4 waves/SIMD.
// amdgpu_waves_per_eu(4,4) pins the register allocator at the 128-VGPR budget:
// R1 showed the 16-row wave shape gets squeezed to 64 VGPRs otherwise, which
// serializes the K/V fragment loads (load->wait->MFMA, ~300cy each) and was a
// 2x regression. Far-from-diagonal kv-tiles (|delta|>=96 => saturated bucket)
// use a wave-uniform constant bias -> no Bls LDS reads for ~13/16 tiles.
__global__ __launch_bounds__(512) __attribute__((amdgpu_waves_per_eu(4, 4)))
void attn_k(
    const unsigned short* __restrict__ Q, const unsigned short* __restrict__ K,
    const unsigned short* __restrict__ Vt, const float* __restrict__ bias,
    unsigned short* __restrict__ ctx)
{
  __shared__ __align__(16) unsigned short Ps[8][16][136];  // wave-private, padded rows
  __shared__ float Bls[4096];                              // bias*log2e - 24 per delta
  const int tid = threadIdx.x;
  const int lane = tid & 63, wave = tid >> 6;
  const int l16 = lane & 15, quad = lane >> 4;
  const int bh = blockIdx.y;
  const int b = bh >> 4, h = bh & 15;
  const int q0 = blockIdx.x << 7;
  const int wq = wave << 4;

  const unsigned short* Qp = Q + (size_t)bh * S_LEN * 64;
  const unsigned short* Kp = K + (size_t)bh * S_LEN * 64;
  const unsigned short* Vp = Vt + (size_t)bh * 64 * S_LEN;
  const float* biasg = bias + h * 4095;

  // stage pre-scaled bias (Bls[j] = bias(delta=j-2047)*log2e - 24)
  for (int i = tid; i < 4095; i += 512)
    Bls[i] = fmaf(biasg[i], 1.44269504f, -24.f);
  __syncthreads();

  const float Bneg = Bls[0], Bpos = Bls[4094];  // saturated-bucket constants

  bf16x8 qf[2];
#pragma unroll
  for (int ks = 0; ks < 2; ++ks)
    qf[ks] = ld_frag(Qp + (size_t)(q0 + wq + l16) * 64 + ks * 32 + quad * 8);

  float l_run[4] = {};
  floatx4 oacc[4] = {};

  const int qwb = q0 + wq;                       // wave's first q row
  const int rbase = 2047 + l16 - qwb - (quad << 2);  // Bls base minus kv0 and i

  for (int kv0 = 0; kv0 < S_LEN; kv0 += 128) {
    floatx4 sac[8] = {};
#pragma unroll
    for (int ks = 0; ks < 2; ++ks) {
      bf16x8 kf[8];
#pragma unroll
      for (int ni = 0; ni < 8; ++ni)
        kf[ni] = ld_frag(Kp + (size_t)(kv0 + ni * 16 + l16) * 64 + ks * 32 + quad * 8);
#pragma unroll
      for (int ni = 0; ni < 8; ++ni)
        sac[ni] = __builtin_amdgcn_mfma_f32_16x16x32_bf16(qf[ks], kf[ni], sac[ni], 0, 0, 0);
    }

    // fixed-max softmax: e = 2^(s*log2e + b); lane-local partial row sums.
    // Wave-uniform fast path when the whole tile sits in a saturated bucket.
    const int dmin = kv0 - (qwb + 15);
    const int dmax = kv0 + 127 - qwb;
    if (dmin >= 96 || dmax <= -96) {
      const float bc = (dmin >= 96) ? Bpos : Bneg;
#pragma unroll
      for (int i = 0; i < 4; ++i) {
        float sum = 0.f;
#pragma unroll
        for (int ni = 0; ni < 8; ++ni) {
          float e = __builtin_amdgcn_exp2f(fmaf(sac[ni][i], 1.44269504f, bc));
          sac[ni][i] = e;
          sum += e;
        }
        l_run[i] += sum;
      }
    } else {
#pragma unroll
      for (int i = 0; i < 4; ++i) {
        const int bbase = kv0 + rbase - i;
        float sum = 0.f;
#pragma unroll
        for (int ni = 0; ni < 8; ++ni) {
          float e = __builtin_amdgcn_exp2f(
              fmaf(sac[ni][i], 1.44269504f, Bls[bbase + ni * 16]));
          sac[ni][i] = e;
          sum += e;
        }
        l_run[i] += sum;
      }
    }

    // P (C/D layout) -> LDS -> A-operand layout, wave-private (no barrier needed)
#pragma unroll
    for (int ni = 0; ni < 8; ++ni)
#pragma unroll
      for (int i = 0; i < 4; ++i)
        Ps[wave][quad * 4 + i][ni * 16 + l16] = f2bf(sac[ni][i]);

#pragma unroll
    for (int ks2 = 0; ks2 < 4; ++ks2) {
      bf16x8 af, vf[4];
      af = *(const bf16x8*)&Ps[wave][l16][ks2 * 32 + quad * 8];
#pragma unroll
      for (int ni = 0; ni < 4; ++ni)
        vf[ni] = ld_frag(Vp + (size_t)(ni * 16 + l16) * S_LEN + kv0 + ks2 * 32 + quad * 8);
#pragma unroll
      for (int ni = 0; ni < 4; ++ni)
        oacc[ni] = __builtin_amdgcn_mfma_f32_16x16x32_bf16(af, vf[ni], oacc[ni], 0, 0, 0);
    }
  }

  // one-time cross-lane l reduction (columns live on the 16 lanes of each quad)
  float linv[4];
#pragma unroll
  for (int i = 0; i < 4; ++i) {
    float ls = l_run[i];
    ls += __shfl_xor(ls, 1);
    ls += __shfl_xor(ls, 2);
    ls += __shfl_xor(ls, 4);
    ls += __shfl_xor(ls, 8);
    linv[i] = 1.f / ls;
  }

#pragma unroll
  for (int ni = 0; ni < 4; ++ni)
#pragma unroll
    for (int i = 0; i < 4; ++i) {
      float v = oacc[ni][i] * linv[i];
      int srow = q0 + wq + quad * 4 + i;
      ctx[((size_t)(b * 2048 + srow)) * 1024 + h * 64 + ni * 16 + l16] = f2bf(v);
    }
}

extern "C" void kernel_launch(void* const* d_in, const int* in_sizes, int n_in,
                              void* d_out, int out_size, void* d_ws, size_t ws_size,
                              hipStream_t stream) {
  char* ws = (char*)d_ws;
  // R2/R6-proven workspace layout, byte-for-byte.
  unsigned short* Xbf  = (unsigned short*)(ws);                    // 8 MB
  unsigned short* Wcat = (unsigned short*)(ws + 8388608);          // 6 MB (Wq^T|Wk^T|Wv^T)
  unsigned short* Wto  = (unsigned short*)(ws + 14680064);         // 2 MB
  unsigned short* Qb   = (unsigned short*)(ws + 16777216);         // 8 MB  (K at +8MB, Vt at +16MB)
  unsigned short* ctx  = (unsigned short*)(ws + 41943040);         // 8 MB
  float*          bias = (float*)(ws + 50331648);                  // 16*4095*4
  int*            flag = (int*)(ws + 50593792);

  unsigned short* Kb  = Qb + 4194304;
  unsigned short* Vtb = Qb + 8388608;

  detect_k<<<1, 256, 0, stream>>>((const unsigned short*)d_in[0], flag);
  conv_x<<<2048, 256, 0, stream>>>(d_in[0], Xbf, flag, 524288);
  transpose_w<<<dim3(32, 32, 4), dim3(32, 8), 0, stream>>>(
      d_in[1], d_in[2], d_in[3], d_in[4], Wcat, Wto, flag);
  bias_k<<<256, 256, 0, stream>>>(d_in[5], bias, flag);

  // fused QKV GEMM: [4096,1024] @ [3072,1024]^T -> Q|K|Vt
  gemm_bt<<<dim3(24, 32), 256, 0, stream>>>(Xbf, Wcat, Qb, 0, flag);

  // flash attention: Q-tile 128, 8 waves/block, 512 blocks (2/CU, 4 waves/SIMD)
  attn_k<<<dim3(16, 32), 512, 0, stream>>>(Qb, Kb, Vtb, bias, ctx);

  // out GEMM: [4096,1024] @ [1024,1024]^T, 128x64 tiles
  gemm_out<<<dim3(16, 32), 256, 0, stream>>>(ctx, Wto, d_out, flag);
}

// Round 3
// 334.089 us; speedup vs baseline: 1.2196x; 1.2162x over previous
//
#include <hip/hip_runtime.h>
#include <math.h>

#define S_LEN 2048
#define DM 1024

typedef __attribute__((ext_vector_type(8))) __bf16 bf16x8;
typedef __attribute__((ext_vector_type(4))) float floatx4;

typedef __attribute__((address_space(1))) const unsigned int g_u32;
typedef __attribute__((address_space(3))) unsigned int l_u32;

__device__ __forceinline__ unsigned short f2bf(float f) {
  union { float f; unsigned int u; } v; v.f = f;
  return (unsigned short)((v.u + 0x7fffu + ((v.u >> 16) & 1u)) >> 16);
}
__device__ __forceinline__ float bf2f(unsigned short u) {
  union { unsigned int u; float f; } v; v.u = ((unsigned int)u) << 16;
  return v.f;
}
__device__ __forceinline__ bf16x8 ld_frag(const unsigned short* p) {
  union { uint4 u; bf16x8 v; } t;
  t.u = *(const uint4*)p;
  return t.v;
}

// ---------------- dtype probe: 1 = buffers are fp32, 0 = bf16 ----------------
__global__ void detect_k(const unsigned short* __restrict__ x, int* __restrict__ flag) {
  __shared__ int cnt;
  if (threadIdx.x == 0) cnt = 0;
  __syncthreads();
  int local = 0;
  for (int i = threadIdx.x; i < 4096; i += 256) {
    unsigned short u = x[i];
    int e = (u >> 7) & 0xFF;
    if (e > 140) local++;
  }
  atomicAdd(&cnt, local);
  __syncthreads();
  if (threadIdx.x == 0) *flag = (cnt > 64) ? 1 : 0;
}

// ---------------- convert hidden_states to bf16 (8 elems/thread) ----------------
__global__ void conv_x(const void* __restrict__ src, unsigned short* __restrict__ dst,
                       const int* __restrict__ flag, int n8) {
  int i = blockIdx.x * 256 + threadIdx.x;
  if (i >= n8) return;
  if (*flag) {
    const float4* s = (const float4*)src;
    float4 a = s[2 * i], b = s[2 * i + 1];
    union { uint4 u4; unsigned short s[8]; } o;
    o.s[0] = f2bf(a.x); o.s[1] = f2bf(a.y); o.s[2] = f2bf(a.z); o.s[3] = f2bf(a.w);
    o.s[4] = f2bf(b.x); o.s[5] = f2bf(b.y); o.s[6] = f2bf(b.z); o.s[7] = f2bf(b.w);
    ((uint4*)dst)[i] = o.u4;
  } else {
    ((uint4*)dst)[i] = ((const uint4*)src)[i];
  }
}

// ---------------- transpose 1024x1024 weights -> bf16 W^T (4 mats, one launch) ----------------
__global__ void transpose_w(const void* __restrict__ s0, const void* __restrict__ s1,
                            const void* __restrict__ s2, const void* __restrict__ s3,
                            unsigned short* __restrict__ Wcat, unsigned short* __restrict__ Wto,
                            const int* __restrict__ flag) {
  __shared__ float tile[32][33];
  const int z = blockIdx.z;
  const void* src = (z == 0) ? s0 : (z == 1) ? s1 : (z == 2) ? s2 : s3;
  unsigned short* dst = (z < 3) ? (Wcat + (size_t)z * 1048576) : Wto;
  const int isf = *flag;
  int x = blockIdx.x * 32 + threadIdx.x;
  int y0 = blockIdx.y * 32;
  for (int i = threadIdx.y; i < 32; i += 8) {
    float v;
    if (isf) v = ((const float*)src)[(size_t)(y0 + i) * DM + x];
    else     v = bf2f(((const unsigned short*)src)[(size_t)(y0 + i) * DM + x]);
    tile[i][threadIdx.x] = v;
  }
  __syncthreads();
  int xo = y0 + threadIdx.x;
  for (int i = threadIdx.y; i < 32; i += 8)
    dst[(size_t)(blockIdx.x * 32 + i) * DM + xo] = f2bf(tile[threadIdx.x][i]);
}

// ---------------- dense relative-position bias table [16][4095] ----------------
__global__ void bias_k(const void* __restrict__ table, float* __restrict__ out,
                       const int* __restrict__ flag) {
  int idx = blockIdx.x * 256 + threadIdx.x;
  if (idx >= 16 * 4095) return;
  int h = idx / 4095;
  int j = idx - h * 4095;
  int delta = j - 2047;            // k - q
  int bucket = (delta > 0) ? 16 : 0;
  int ad = (delta < 0) ? -delta : delta;
  int smallv;
  if (ad < 8) smallv = ad;
  else {
    int l = (int)(log((double)ad * 0.125) * (8.0 / log(16.0)));
    smallv = 8 + l;
    if (smallv > 15) smallv = 15;
  }
  bucket += smallv;
  float v;
  if (*flag) v = ((const float*)table)[bucket * 16 + h];
  else       v = bf2f(((const unsigned short*)table)[bucket * 16 + h]);
  out[idx] = v;
}

// ---------------- bf16 GEMM, m97-style (global_load_lds, unpadded LDS) ----------------
// mode 0: fused QKV, N=3072, C = Qb base (Q|K|V contiguous, V transposed)
__global__ __launch_bounds__(256) void gemm_bt(
    const unsigned short* __restrict__ A, const unsigned short* __restrict__ Bt,
    void* __restrict__ C, int mode, const int* __restrict__ flag)
{
  __shared__ __align__(16) unsigned short As[128 * 64];
  __shared__ __align__(16) unsigned short Bs[128 * 64];
  const int tid = threadIdx.x;
  const int lane = tid & 63, wave = tid >> 6;
  const int l16 = lane & 15, quad = lane >> 4;
  const int wm = (wave >> 1) << 6, wn = (wave & 1) << 6;
  const int m0 = blockIdx.y << 7, n0 = blockIdx.x << 7;
  const int lrow = lane >> 3, lcol = (lane & 7) << 3;

  floatx4 acc[4][4] = {};

  for (int k0 = 0; k0 < 1024; k0 += 64) {
    __syncthreads();
#pragma unroll
    for (int i = 0; i < 4; ++i) {
      int r0 = wave * 32 + i * 8;
      __builtin_amdgcn_global_load_lds(
          (g_u32*)(const void*)(A + (size_t)(m0 + r0 + lrow) * 1024 + k0 + lcol),
          (l_u32*)(void*)&As[r0 * 64], 16, 0, 0);
      __builtin_amdgcn_global_load_lds(
          (g_u32*)(const void*)(Bt + (size_t)(n0 + r0 + lrow) * 1024 + k0 + lcol),
          (l_u32*)(void*)&Bs[r0 * 64], 16, 0, 0);
    }
    __syncthreads();
#pragma unroll
    for (int ks = 0; ks < 2; ++ks) {
      bf16x8 a[4], b[4];
#pragma unroll
      for (int mi = 0; mi < 4; ++mi)
        a[mi] = *(const bf16x8*)&As[(wm + mi * 16 + l16) * 64 + ks * 32 + quad * 8];
#pragma unroll
      for (int ni = 0; ni < 4; ++ni)
        b[ni] = *(const bf16x8*)&Bs[(wn + ni * 16 + l16) * 64 + ks * 32 + quad * 8];
#pragma unroll
      for (int mi = 0; mi < 4; ++mi)
#pragma unroll
        for (int ni = 0; ni < 4; ++ni)
          acc[mi][ni] = __builtin_amdgcn_mfma_f32_16x16x32_bf16(a[mi], b[ni], acc[mi][ni], 0, 0, 0);
    }
  }

  if (mode == 0) {
    unsigned short* Cs = (unsigned short*)C;
    const int mat = n0 >> 10;           // uniform per block
#pragma unroll
    for (int mi = 0; mi < 4; ++mi)
#pragma unroll
      for (int ni = 0; ni < 4; ++ni)
#pragma unroll
        for (int i = 0; i < 4; ++i) {
          int m = m0 + wm + mi * 16 + quad * 4 + i;
          int n = (n0 & 1023) + wn + ni * 16 + l16;
          int b = m >> 11, s = m & 2047, h = n >> 6, d = n & 63;
          unsigned short v = f2bf(acc[mi][ni][i]);
          if (mat < 2)
            Cs[(size_t)mat * 4194304 + (((size_t)(b * 16 + h)) * 2048 + s) * 64 + d] = v;
          else
            Cs[(size_t)2 * 4194304 + (((size_t)(b * 16 + h)) * 64 + d) * 2048 + s] = v;
        }
  } else {
    const int isf = *flag;
#pragma unroll
    for (int mi = 0; mi < 4; ++mi)
#pragma unroll
      for (int ni = 0; ni < 4; ++ni)
#pragma unroll
        for (int i = 0; i < 4; ++i) {
          int m = m0 + wm + mi * 16 + quad * 4 + i;
          int n = n0 + wn + ni * 16 + l16;
          size_t idx = (size_t)m * 1024 + n;
          float v = acc[mi][ni][i];
          if (isf) ((float*)C)[idx] = v;
          else     ((unsigned short*)C)[idx] = f2bf(v);
        }
  }
}

// ---------------- out GEMM, 128x64 tiles (512 blocks = 2/CU) ----------------
__global__ __launch_bounds__(256) void gemm_out(
    const unsigned short* __restrict__ A, const unsigned short* __restrict__ Bt,
    void* __restrict__ C, const int* __restrict__ flag)
{
  __shared__ __align__(16) unsigned short As[128 * 64];
  __shared__ __align__(16) unsigned short Bs[64 * 64];
  const int tid = threadIdx.x;
  const int lane = tid & 63, wave = tid >> 6;
  const int l16 = lane & 15, quad = lane >> 4;
  const int wm = (wave >> 1) << 6, wn = (wave & 1) << 5;
  const int m0 = blockIdx.y << 7, n0 = blockIdx.x << 6;
  const int lrow = lane >> 3, lcol = (lane & 7) << 3;

  floatx4 acc[4][2] = {};

  for (int k0 = 0; k0 < 1024; k0 += 64) {
    __syncthreads();
#pragma unroll
    for (int i = 0; i < 4; ++i) {
      int r0 = wave * 32 + i * 8;
      __builtin_amdgcn_global_load_lds(
          (g_u32*)(const void*)(A + (size_t)(m0 + r0 + lrow) * 1024 + k0 + lcol),
          (l_u32*)(void*)&As[r0 * 64], 16, 0, 0);
    }
#pragma unroll
    for (int i = 0; i < 2; ++i) {
      int r0 = wave * 16 + i * 8;
      __builtin_amdgcn_global_load_lds(
          (g_u32*)(const void*)(Bt + (size_t)(n0 + r0 + lrow) * 1024 + k0 + lcol),
          (l_u32*)(void*)&Bs[r0 * 64], 16, 0, 0);
    }
    __syncthreads();
#pragma unroll
    for (int ks = 0; ks < 2; ++ks) {
      bf16x8 a[4], b[2];
#pragma unroll
      for (int mi = 0; mi < 4; ++mi)
        a[mi] = *(const bf16x8*)&As[(wm + mi * 16 + l16) * 64 + ks * 32 + quad * 8];
#pragma unroll
      for (int ni = 0; ni < 2; ++ni)
        b[ni] = *(const bf16x8*)&Bs[(wn + ni * 16 + l16) * 64 + ks * 32 + quad * 8];
#pragma unroll
      for (int mi = 0; mi < 4; ++mi)
#pragma unroll
        for (int ni = 0; ni < 2; ++ni)
          acc[mi][ni] = __builtin_amdgcn_mfma_f32_16x16x32_bf16(a[mi], b[ni], acc[mi][ni], 0, 0, 0);
    }
  }

  const int isf = *flag;
#pragma unroll
  for (int mi = 0; mi < 4; ++mi)
#pragma unroll
    for (int ni = 0; ni < 2; ++ni)
#pragma unroll
      for (int i = 0; i < 4; ++i) {
        int m = m0 + wm + mi * 16 + quad * 4 + i;
        int n = n0 + wn + ni * 16 + l16;
        size_t idx = (size_t)m * 1024 + n;
        float v = acc[mi][ni][i];
        if (isf) ((float*)C)[idx] = v;
        else     ((unsigned short*)C)[idx] = f2bf(v);
      }
}

// ---------------- flash attention: R0 shape + software pipeline ----------------
// 4 waves x 32 q-rows, grid (16,32) = 512 blocks = 2 blocks/CU. LDS caps
// occupancy at 2 blocks/CU regardless of VGPRs, so trade registers for ILP:
// __launch_bounds__(256,2) pins the allocator at the 2-waves/EU budget (<=256
// VGPR) -- R1/R2 proved the scheduler otherwise squeezes to 64 and serializes
// loads. Pipeline per kv-tile: K(ks0) issued under PV of previous tile; all 16
// V loads issued under softmax; P-store->ds_read is the only residual dep.
#define LOAD_K(kv0, ks, kfarr)                                                 \
  _Pragma("unroll")                                                            \
  for (int ni = 0; ni < 8; ++ni)                                               \
    kfarr[ni] = ld_frag(Kp + (size_t)((kv0) + ni * 16 + l16) * 64 + (ks) * 32 + quad * 8);

#define QK_MFMA(ks, kfarr)                                                     \
  _Pragma("unroll")                                                            \
  for (int mi = 0; mi < 2; ++mi)                                               \
    _Pragma("unroll")                                                          \
    for (int ni = 0; ni < 8; ++ni)                                             \
      sac[mi][ni] = __builtin_amdgcn_mfma_f32_16x16x32_bf16(qf[mi][ks], kfarr[ni], sac[mi][ni], 0, 0, 0);

#define LOAD_V(kv0)                                                            \
  _Pragma("unroll")                                                            \
  for (int j = 0; j < 16; ++j)                                                 \
    vf[j] = ld_frag(Vp + (size_t)((j & 3) * 16 + l16) * S_LEN + (kv0) + (j >> 2) * 32 + quad * 8);

#define PV_STEP()                                                              \
  _Pragma("unroll")                                                            \
  for (int ks2 = 0; ks2 < 4; ++ks2) {                                          \
    bf16x8 af[2];                                                              \
    _Pragma("unroll")                                                          \
    for (int mi = 0; mi < 2; ++mi)                                             \
      af[mi] = *(const bf16x8*)&Ps[wave][mi * 16 + l16][ks2 * 32 + quad * 8];  \
    _Pragma("unroll")                                                          \
    for (int mi = 0; mi < 2; ++mi)                                             \
      _Pragma("unroll")                                                        \
      for (int ni = 0; ni < 4; ++ni)                                           \
        oacc[mi][ni] = __builtin_amdgcn_mfma_f32_16x16x32_bf16(af[mi], vf[ks2 * 4 + ni], oacc[mi][ni], 0, 0, 0); \
  }

#define SOFTMAX_P(kv0)                                                         \
  {                                                                            \
    const int dmin = (kv0) - (qwb + 31);                                       \
    const int dmax = (kv0) + 127 - qwb;                                        \
    if (dmin >= 96 || dmax <= -96) {                                           \
      const float bc = (dmin >= 96) ? Bpos : Bneg;                             \
      _Pragma("unroll")                                                        \
      for (int mi = 0; mi < 2; ++mi)                                           \
        _Pragma("unroll")                                                      \
        for (int i = 0; i < 4; ++i) {                                          \
          float sum = 0.f;                                                     \
          _Pragma("unroll")                                                    \
          for (int ni = 0; ni < 8; ++ni) {                                     \
            float e = __builtin_amdgcn_exp2f(fmaf(sac[mi][ni][i], 1.44269504f, bc)); \
            sac[mi][ni][i] = e; sum += e;                                      \
          }                                                                    \
          l_run[mi][i] += sum;                                                 \
        }                                                                      \
    } else {                                                                   \
      _Pragma("unroll")                                                        \
      for (int mi = 0; mi < 2; ++mi)                                           \
        _Pragma("unroll")                                                      \
        for (int i = 0; i < 4; ++i) {                                          \
          const int bbase = (kv0) + rbase - i - mi * 16;                       \
          float sum = 0.f;                                                     \
          _Pragma("unroll")                                                    \
          for (int ni = 0; ni < 8; ++ni) {                                     \
            float e = __builtin_amdgcn_exp2f(fmaf(sac[mi][ni][i], 1.44269504f, Bls[bbase + ni * 16])); \
            sac[mi][ni][i] = e; sum += e;                                      \
          }                                                                    \
          l_run[mi][i] += sum;                                                 \
        }                                                                      \
    }                                                                          \
    _Pragma("unroll")                                                          \
    for (int mi = 0; mi < 2; ++mi)                                             \
      _Pragma("unroll")                                                        \
      for (int ni = 0; ni < 8; ++ni)                                           \
        _Pragma("unroll")                                                      \
        for (int i = 0; i < 4; ++i)                                            \
          Ps[wave][mi * 16 + quad * 4 + i][ni * 16 + l16] = f2bf(sac[mi][ni][i]); \
  }

__global__ __launch_bounds__(256, 2) void attn_k(
    const unsigned short* __restrict__ Q, const unsigned short* __restrict__ K,
    const unsigned short* __restrict__ Vt, const float* __restrict__ bias,
    unsigned short* __restrict__ ctx)
{
  __shared__ __align__(16) unsigned short Ps[4][32][136];  // wave-private, padded rows
  __shared__ float Bls[4096];                              // bias*log2e - 24 per delta
  const int tid = threadIdx.x;
  const int lane = tid & 63, wave = tid >> 6;
  const int l16 = lane & 15, quad = lane >> 4;
  const int bh = blockIdx.y;
  const int b = bh >> 4, h = bh & 15;
  const int q0 = blockIdx.x << 7;
  const int wq = wave << 5;

  const unsigned short* Qp = Q + (size_t)bh * S_LEN * 64;
  const unsigned short* Kp = K + (size_t)bh * S_LEN * 64;
  const unsigned short* Vp = Vt + (size_t)bh * 64 * S_LEN;
  const float* biasg = bias + h * 4095;

  // stage pre-scaled bias (Bls[j] = bias(delta=j-2047)*log2e - 24)
  for (int i = tid; i < 4095; i += 256)
    Bls[i] = fmaf(biasg[i], 1.44269504f, -24.f);
  __syncthreads();

  const float Bneg = Bls[0], Bpos = Bls[4094];  // saturated-bucket constants

  bf16x8 qf[2][2];
#pragma unroll
  for (int mi = 0; mi < 2; ++mi)
#pragma unroll
    for (int ks = 0; ks < 2; ++ks)
      qf[mi][ks] = ld_frag(Qp + (size_t)(q0 + wq + mi * 16 + l16) * 64 + ks * 32 + quad * 8);

  float l_run[2][4] = {};
  floatx4 oacc[2][4] = {};
  bf16x8 vf[16];

  const int qwb = q0 + wq;                           // wave's first q row
  const int rbase = 2047 + l16 - qwb - (quad << 2);  // Bls base minus kv0, mi, i

  // ---- prologue: tile 0 (no previous PV to hide K under) ----
  {
    floatx4 sac[2][8] = {};
    bf16x8 kf0[8], kf1[8];
    LOAD_K(0, 0, kf0);
    QK_MFMA(0, kf0);
    LOAD_K(0, 1, kf1);
    QK_MFMA(1, kf1);
    LOAD_V(0);
    SOFTMAX_P(0);
  }

  // ---- pipelined main loop ----
  for (int kv0 = 128; kv0 < S_LEN; kv0 += 128) {
    floatx4 sac[2][8] = {};
    bf16x8 kf0[8], kf1[8];
    LOAD_K(kv0, 0, kf0);   // K latency hides under PV(prev)
    PV_STEP();             // consumes vf(prev), Ps(prev)
    QK_MFMA(0, kf0);
    LOAD_K(kv0, 1, kf1);
    QK_MFMA(1, kf1);
    LOAD_V(kv0);           // V latency hides under softmax + P-store
    SOFTMAX_P(kv0);
  }

  // ---- epilogue: PV of last tile ----
  PV_STEP();

  // one-time cross-lane l reduction (columns live on the 16 lanes of each quad)
  float linv[2][4];
#pragma unroll
  for (int mi = 0; mi < 2; ++mi)
#pragma unroll
    for (int i = 0; i < 4; ++i) {
      float ls = l_run[mi][i];
      ls += __shfl_xor(ls, 1);
      ls += __shfl_xor(ls, 2);
      ls += __shfl_xor(ls, 4);
      ls += __shfl_xor(ls, 8);
      linv[mi][i] = 1.f / ls;
    }

#pragma unroll
  for (int mi = 0; mi < 2; ++mi)
#pragma unroll
    for (int ni = 0; ni < 4; ++ni)
#pragma unroll
      for (int i = 0; i < 4; ++i) {
        float v = oacc[mi][ni][i] * linv[mi][i];
        int srow = q0 + wq + mi * 16 + quad * 4 + i;
        ctx[((size_t)(b * 2048 + srow)) * 1024 + h * 64 + ni * 16 + l16] = f2bf(v);
      }
}

extern "C" void kernel_launch(void* const* d_in, const int* in_sizes, int n_in,
                              void* d_out, int out_size, void* d_ws, size_t ws_size,
                              hipStream_t stream) {
  char* ws = (char*)d_ws;
  // R2/R6-proven workspace layout, byte-for-byte.
  unsigned short* Xbf  = (unsigned short*)(ws);                    // 8 MB
  unsigned short* Wcat = (unsigned short*)(ws + 8388608);          // 6 MB (Wq^T|Wk^T|Wv^T)
  unsigned short* Wto  = (unsigned short*)(ws + 14680064);         // 2 MB
  unsigned short* Qb   = (unsigned short*)(ws + 16777216);         // 8 MB  (K at +8MB, Vt at +16MB)
  unsigned short* ctx  = (unsigned short*)(ws + 41943040);         // 8 MB
  float*          bias = (float*)(ws + 50331648);                  // 16*4095*4
  int*            flag = (int*)(ws + 50593792);

  unsigned short* Kb  = Qb + 4194304;
  unsigned short* Vtb = Qb + 8388608;

  detect_k<<<1, 256, 0, stream>>>((const unsigned short*)d_in[0], flag);
  conv_x<<<2048, 256, 0, stream>>>(d_in[0], Xbf, flag, 524288);
  transpose_w<<<dim3(32, 32, 4), dim3(32, 8), 0, stream>>>(
      d_in[1], d_in[2], d_in[3], d_in[4], Wcat, Wto, flag);
  bias_k<<<256, 256, 0, stream>>>(d_in[5], bias, flag);

  // fused QKV GEMM: [4096,1024] @ [3072,1024]^T -> Q|K|Vt
  gemm_bt<<<dim3(24, 32), 256, 0, stream>>>(Xbf, Wcat, Qb, 0, flag);

  // flash attention: R0 shape (4 waves x 32 rows), software-pipelined
  attn_k<<<dim3(16, 32), 256, 0, stream>>>(Qb, Kb, Vtb, bias, ctx);

  // out GEMM: [4096,1024] @ [1024,1024]^T, 128x64 tiles
  gemm_out<<<dim3(16, 32), 256, 0, stream>>>(ctx, Wto, d_out, flag);
}

// Round 4
// 303.287 us; speedup vs baseline: 1.3435x; 1.1016x over previous
//
#include <hip/hip_runtime.h>
#include <math.h>

#define S_LEN 2048
#define DM 1024

typedef __attribute__((ext_vector_type(8))) __bf16 bf16x8;
typedef __attribute__((ext_vector_type(4))) float floatx4;

typedef __attribute__((address_space(1))) const unsigned int g_u32;
typedef __attribute__((address_space(3))) unsigned int l_u32;

__device__ __forceinline__ unsigned short f2bf(float f) {
  union { float f; unsigned int u; } v; v.f = f;
  return (unsigned short)((v.u + 0x7fffu + ((v.u >> 16) & 1u)) >> 16);
}
__device__ __forceinline__ float bf2f(unsigned short u) {
  union { unsigned int u; float f; } v; v.u = ((unsigned int)u) << 16;
  return v.f;
}
__device__ __forceinline__ bf16x8 ld_frag(const unsigned short* p) {
  union { uint4 u; bf16x8 v; } t;
  t.u = *(const uint4*)p;
  return t.v;
}

// ---------------- dtype probe: 1 = buffers are fp32, 0 = bf16 ----------------
__global__ void detect_k(const unsigned short* __restrict__ x, int* __restrict__ flag) {
  __shared__ int cnt;
  if (threadIdx.x == 0) cnt = 0;
  __syncthreads();
  int local = 0;
  for (int i = threadIdx.x; i < 4096; i += 256) {
    unsigned short u = x[i];
    int e = (u >> 7) & 0xFF;
    if (e > 140) local++;
  }
  atomicAdd(&cnt, local);
  __syncthreads();
  if (threadIdx.x == 0) *flag = (cnt > 64) ? 1 : 0;
}

// ---------------- convert hidden_states to bf16 (8 elems/thread) ----------------
__global__ void conv_x(const void* __restrict__ src, unsigned short* __restrict__ dst,
                       const int* __restrict__ flag, int n8) {
  int i = blockIdx.x * 256 + threadIdx.x;
  if (i >= n8) return;
  if (*flag) {
    const float4* s = (const float4*)src;
    float4 a = s[2 * i], b = s[2 * i + 1];
    union { uint4 u4; unsigned short s[8]; } o;
    o.s[0] = f2bf(a.x); o.s[1] = f2bf(a.y); o.s[2] = f2bf(a.z); o.s[3] = f2bf(a.w);
    o.s[4] = f2bf(b.x); o.s[5] = f2bf(b.y); o.s[6] = f2bf(b.z); o.s[7] = f2bf(b.w);
    ((uint4*)dst)[i] = o.u4;
  } else {
    ((uint4*)dst)[i] = ((const uint4*)src)[i];
  }
}

// ---------------- transpose 1024x1024 weights -> bf16 W^T (4 mats, one launch) ----------------
__global__ void transpose_w(const void* __restrict__ s0, const void* __restrict__ s1,
                            const void* __restrict__ s2, const void* __restrict__ s3,
                            unsigned short* __restrict__ Wcat, unsigned short* __restrict__ Wto,
                            const int* __restrict__ flag) {
  __shared__ float tile[32][33];
  const int z = blockIdx.z;
  const void* src = (z == 0) ? s0 : (z == 1) ? s1 : (z == 2) ? s2 : s3;
  unsigned short* dst = (z < 3) ? (Wcat + (size_t)z * 1048576) : Wto;
  const int isf = *flag;
  int x = blockIdx.x * 32 + threadIdx.x;
  int y0 = blockIdx.y * 32;
  for (int i = threadIdx.y; i < 32; i += 8) {
    float v;
    if (isf) v = ((const float*)src)[(size_t)(y0 + i) * DM + x];
    else     v = bf2f(((const unsigned short*)src)[(size_t)(y0 + i) * DM + x]);
    tile[i][threadIdx.x] = v;
  }
  __syncthreads();
  int xo = y0 + threadIdx.x;
  for (int i = threadIdx.y; i < 32; i += 8)
    dst[(size_t)(blockIdx.x * 32 + i) * DM + xo] = f2bf(tile[threadIdx.x][i]);
}

// ---------------- dense relative-position bias table [16][4095] ----------------
__global__ void bias_k(const void* __restrict__ table, float* __restrict__ out,
                       const int* __restrict__ flag) {
  int idx = blockIdx.x * 256 + threadIdx.x;
  if (idx >= 16 * 4095) return;
  int h = idx / 4095;
  int j = idx - h * 4095;
  int delta = j - 2047;            // k - q
  int bucket = (delta > 0) ? 16 : 0;
  int ad = (delta < 0) ? -delta : delta;
  int smallv;
  if (ad < 8) smallv = ad;
  else {
    int l = (int)(log((double)ad * 0.125) * (8.0 / log(16.0)));
    smallv = 8 + l;
    if (smallv > 15) smallv = 15;
  }
  bucket += smallv;
  float v;
  if (*flag) v = ((const float*)table)[bucket * 16 + h];
  else       v = bf2f(((const unsigned short*)table)[bucket * 16 + h]);
  out[idx] = v;
}

// ---------------- bf16 GEMM, m97-style (global_load_lds, unpadded LDS) ----------------
// mode 0: fused QKV, N=3072, C = Qb base (Q|K|V contiguous, V transposed)
__global__ __launch_bounds__(256) void gemm_bt(
    const unsigned short* __restrict__ A, const unsigned short* __restrict__ Bt,
    void* __restrict__ C, int mode, const int* __restrict__ flag)
{
  __shared__ __align__(16) unsigned short As[128 * 64];
  __shared__ __align__(16) unsigned short Bs[128 * 64];
  const int tid = threadIdx.x;
  const int lane = tid & 63, wave = tid >> 6;
  const int l16 = lane & 15, quad = lane >> 4;
  const int wm = (wave >> 1) << 6, wn = (wave & 1) << 6;
  const int m0 = blockIdx.y << 7, n0 = blockIdx.x << 7;
  const int lrow = lane >> 3, lcol = (lane & 7) << 3;

  floatx4 acc[4][4] = {};

  for (int k0 = 0; k0 < 1024; k0 += 64) {
    __syncthreads();
#pragma unroll
    for (int i = 0; i < 4; ++i) {
      int r0 = wave * 32 + i * 8;
      __builtin_amdgcn_global_load_lds(
          (g_u32*)(const void*)(A + (size_t)(m0 + r0 + lrow) * 1024 + k0 + lcol),
          (l_u32*)(void*)&As[r0 * 64], 16, 0, 0);
      __builtin_amdgcn_global_load_lds(
          (g_u32*)(const void*)(Bt + (size_t)(n0 + r0 + lrow) * 1024 + k0 + lcol),
          (l_u32*)(void*)&Bs[r0 * 64], 16, 0, 0);
    }
    __syncthreads();
#pragma unroll
    for (int ks = 0; ks < 2; ++ks) {
      bf16x8 a[4], b[4];
#pragma unroll
      for (int mi = 0; mi < 4; ++mi)
        a[mi] = *(const bf16x8*)&As[(wm + mi * 16 + l16) * 64 + ks * 32 + quad * 8];
#pragma unroll
      for (int ni = 0; ni < 4; ++ni)
        b[ni] = *(const bf16x8*)&Bs[(wn + ni * 16 + l16) * 64 + ks * 32 + quad * 8];
#pragma unroll
      for (int mi = 0; mi < 4; ++mi)
#pragma unroll
        for (int ni = 0; ni < 4; ++ni)
          acc[mi][ni] = __builtin_amdgcn_mfma_f32_16x16x32_bf16(a[mi], b[ni], acc[mi][ni], 0, 0, 0);
    }
  }

  if (mode == 0) {
    unsigned short* Cs = (unsigned short*)C;
    const int mat = n0 >> 10;           // uniform per block
#pragma unroll
    for (int mi = 0; mi < 4; ++mi)
#pragma unroll
      for (int ni = 0; ni < 4; ++ni)
#pragma unroll
        for (int i = 0; i < 4; ++i) {
          int m = m0 + wm + mi * 16 + quad * 4 + i;
          int n = (n0 & 1023) + wn + ni * 16 + l16;
          int b = m >> 11, s = m & 2047, h = n >> 6, d = n & 63;
          unsigned short v = f2bf(acc[mi][ni][i]);
          if (mat < 2)
            Cs[(size_t)mat * 4194304 + (((size_t)(b * 16 + h)) * 2048 + s) * 64 + d] = v;
          else
            Cs[(size_t)2 * 4194304 + (((size_t)(b * 16 + h)) * 64 + d) * 2048 + s] = v;
        }
  } else {
    const int isf = *flag;
#pragma unroll
    for (int mi = 0; mi < 4; ++mi)
#pragma unroll
      for (int ni = 0; ni < 4; ++ni)
#pragma unroll
        for (int i = 0; i < 4; ++i) {
          int m = m0 + wm + mi * 16 + quad * 4 + i;
          int n = n0 + wn + ni * 16 + l16;
          size_t idx = (size_t)m * 1024 + n;
          float v = acc[mi][ni][i];
          if (isf) ((float*)C)[idx] = v;
          else     ((unsigned short*)C)[idx] = f2bf(v);
        }
  }
}

// ---------------- out GEMM, 128x64 tiles (512 blocks = 2/CU) ----------------
__global__ __launch_bounds__(256) void gemm_out(
    const unsigned short* __restrict__ A, const unsigned short* __restrict__ Bt,
    void* __restrict__ C, const int* __restrict__ flag)
{
  __shared__ __align__(16) unsigned short As[128 * 64];
  __shared__ __align__(16) unsigned short Bs[64 * 64];
  const int tid = threadIdx.x;
  const int lane = tid & 63, wave = tid >> 6;
  const int l16 = lane & 15, quad = lane >> 4;
  const int wm = (wave >> 1) << 6, wn = (wave & 1) << 5;
  const int m0 = blockIdx.y << 7, n0 = blockIdx.x << 6;
  const int lrow = lane >> 3, lcol = (lane & 7) << 3;

  floatx4 acc[4][2] = {};

  for (int k0 = 0; k0 < 1024; k0 += 64) {
    __syncthreads();
#pragma unroll
    for (int i = 0; i < 4; ++i) {
      int r0 = wave * 32 + i * 8;
      __builtin_amdgcn_global_load_lds(
          (g_u32*)(const void*)(A + (size_t)(m0 + r0 + lrow) * 1024 + k0 + lcol),
          (l_u32*)(void*)&As[r0 * 64], 16, 0, 0);
    }
#pragma unroll
    for (int i = 0; i < 2; ++i) {
      int r0 = wave * 16 + i * 8;
      __builtin_amdgcn_global_load_lds(
          (g_u32*)(const void*)(Bt + (size_t)(n0 + r0 + lrow) * 1024 + k0 + lcol),
          (l_u32*)(void*)&Bs[r0 * 64], 16, 0, 0);
    }
    __syncthreads();
#pragma unroll
    for (int ks = 0; ks < 2; ++ks) {
      bf16x8 a[4], b[2];
#pragma unroll
      for (int mi = 0; mi < 4; ++mi)
        a[mi] = *(const bf16x8*)&As[(wm + mi * 16 + l16) * 64 + ks * 32 + quad * 8];
#pragma unroll
      for (int ni = 0; ni < 2; ++ni)
        b[ni] = *(const bf16x8*)&Bs[(wn + ni * 16 + l16) * 64 + ks * 32 + quad * 8];
#pragma unroll
      for (int mi = 0; mi < 4; ++mi)
#pragma unroll
        for (int ni = 0; ni < 2; ++ni)
          acc[mi][ni] = __builtin_amdgcn_mfma_f32_16x16x32_bf16(a[mi], b[ni], acc[mi][ni], 0, 0, 0);
    }
  }

  const int isf = *flag;
#pragma unroll
  for (int mi = 0; mi < 4; ++mi)
#pragma unroll
    for (int ni = 0; ni < 2; ++ni)
#pragma unroll
      for (int i = 0; i < 4; ++i) {
        int m = m0 + wm + mi * 16 + quad * 4 + i;
        int n = n0 + wn + ni * 16 + l16;
        size_t idx = (size_t)m * 1024 + n;
        float v = acc[mi][ni][i];
        if (isf) ((float*)C)[idx] = v;
        else     ((unsigned short*)C)[idx] = f2bf(v);
      }
}

// ---------------- flash attention: R0 shape + spill-free software pipeline ----------------
// 4 waves x 32 q-rows, grid (16,32). R3's pipeline raised HBM BW 610->1020 GB/s
// (overlap works) but vf[16]+kf0+kf1 = 128 live arch VGPRs on top of addressing
// spilled ~11 regs/tile to scratch (WRITE_SIZE 8->99 MB). Fix: V split into two
// 4-ks2 halves (vfA/vfB, 32 regs each) so peak live set stays ~110:
//   LOAD_K0 -> PV_B(t-1) ; LOAD_K1 -> QK0 ; QK1 ; LOAD_VA -> softmax ; LOAD_VB -> PV_A
// Every load batch issues under independent compute.
#define LOAD_K(kv0, ks, kfarr)                                                 \
  _Pragma("unroll")                                                            \
  for (int ni = 0; ni < 8; ++ni)                                               \
    kfarr[ni] = ld_frag(Kp + (size_t)((kv0) + ni * 16 + l16) * 64 + (ks) * 32 + quad * 8);

#define QK_MFMA(ks, kfarr)                                                     \
  _Pragma("unroll")                                                            \
  for (int mi = 0; mi < 2; ++mi)                                               \
    _Pragma("unroll")                                                          \
    for (int ni = 0; ni < 8; ++ni)                                             \
      sac[mi][ni] = __builtin_amdgcn_mfma_f32_16x16x32_bf16(qf[mi][ks], kfarr[ni], sac[mi][ni], 0, 0, 0);

#define LOAD_VH(kv0, varr, base)                                               \
  _Pragma("unroll")                                                            \
  for (int j = 0; j < 8; ++j)                                                  \
    varr[j] = ld_frag(Vp + (size_t)((j & 3) * 16 + l16) * S_LEN + (kv0) + ((base) + (j >> 2)) * 32 + quad * 8);

#define PV_HALF(varr, base)                                                    \
  _Pragma("unroll")                                                            \
  for (int k2 = 0; k2 < 2; ++k2) {                                             \
    bf16x8 af[2];                                                              \
    _Pragma("unroll")                                                          \
    for (int mi = 0; mi < 2; ++mi)                                             \
      af[mi] = *(const bf16x8*)&Ps[wave][mi * 16 + l16][((base) + k2) * 32 + quad * 8]; \
    _Pragma("unroll")                                                          \
    for (int mi = 0; mi < 2; ++mi)                                             \
      _Pragma("unroll")                                                        \
      for (int ni = 0; ni < 4; ++ni)                                           \
        oacc[mi][ni] = __builtin_amdgcn_mfma_f32_16x16x32_bf16(af[mi], varr[k2 * 4 + ni], oacc[mi][ni], 0, 0, 0); \
  }

#define SOFTMAX_P(kv0)                                                         \
  {                                                                            \
    const int dmin = (kv0) - (qwb + 31);                                       \
    const int dmax = (kv0) + 127 - qwb;                                        \
    if (dmin >= 96 || dmax <= -96) {                                           \
      const float bc = (dmin >= 96) ? Bpos : Bneg;                             \
      _Pragma("unroll")                                                        \
      for (int mi = 0; mi < 2; ++mi)                                           \
        _Pragma("unroll")                                                      \
        for (int i = 0; i < 4; ++i) {                                          \
          float sum = 0.f;                                                     \
          _Pragma("unroll")                                                    \
          for (int ni = 0; ni < 8; ++ni) {                                     \
            float e = __builtin_amdgcn_exp2f(fmaf(sac[mi][ni][i], 1.44269504f, bc)); \
            sac[mi][ni][i] = e; sum += e;                                      \
          }                                                                    \
          l_run[mi][i] += sum;                                                 \
        }                                                                      \
    } else {                                                                   \
      _Pragma("unroll")                                                        \
      for (int mi = 0; mi < 2; ++mi)                                           \
        _Pragma("unroll")                                                      \
        for (int i = 0; i < 4; ++i) {                                          \
          const int bbase = (kv0) + rbase - i - mi * 16;                       \
          float sum = 0.f;                                                     \
          _Pragma("unroll")                                                    \
          for (int ni = 0; ni < 8; ++ni) {                                     \
            float e = __builtin_amdgcn_exp2f(fmaf(sac[mi][ni][i], 1.44269504f, Bls[bbase + ni * 16])); \
            sac[mi][ni][i] = e; sum += e;                                      \
          }                                                                    \
          l_run[mi][i] += sum;                                                 \
        }                                                                      \
    }                                                                          \
    _Pragma("unroll")                                                          \
    for (int mi = 0; mi < 2; ++mi)                                             \
      _Pragma("unroll")                                                        \
      for (int ni = 0; ni < 8; ++ni)                                           \
        _Pragma("unroll")                                                      \
        for (int i = 0; i < 4; ++i)                                            \
          Ps[wave][mi * 16 + quad * 4 + i][ni * 16 + l16] = f2bf(sac[mi][ni][i]); \
  }

__global__ __launch_bounds__(256, 2) void attn_k(
    const unsigned short* __restrict__ Q, const unsigned short* __restrict__ K,
    const unsigned short* __restrict__ Vt, const float* __restrict__ bias,
    unsigned short* __restrict__ ctx)
{
  __shared__ __align__(16) unsigned short Ps[4][32][136];  // wave-private, padded rows
  __shared__ float Bls[4096];                              // bias*log2e - 24 per delta
  const int tid = threadIdx.x;
  const int lane = tid & 63, wave = tid >> 6;
  const int l16 = lane & 15, quad = lane >> 4;
  const int bh = blockIdx.y;
  const int b = bh >> 4, h = bh & 15;
  const int q0 = blockIdx.x << 7;
  const int wq = wave << 5;

  const unsigned short* Qp = Q + (size_t)bh * S_LEN * 64;
  const unsigned short* Kp = K + (size_t)bh * S_LEN * 64;
  const unsigned short* Vp = Vt + (size_t)bh * 64 * S_LEN;
  const float* biasg = bias + h * 4095;

  // stage pre-scaled bias (Bls[j] = bias(delta=j-2047)*log2e - 24)
  for (int i = tid; i < 4095; i += 256)
    Bls[i] = fmaf(biasg[i], 1.44269504f, -24.f);
  __syncthreads();

  const float Bneg = Bls[0], Bpos = Bls[4094];  // saturated-bucket constants

  bf16x8 qf[2][2];
#pragma unroll
  for (int mi = 0; mi < 2; ++mi)
#pragma unroll
    for (int ks = 0; ks < 2; ++ks)
      qf[mi][ks] = ld_frag(Qp + (size_t)(q0 + wq + mi * 16 + l16) * 64 + ks * 32 + quad * 8);

  float l_run[2][4] = {};
  floatx4 oacc[2][4] = {};
  bf16x8 vfA[8], vfB[8];

  const int qwb = q0 + wq;                           // wave's first q row
  const int rbase = 2047 + l16 - qwb - (quad << 2);  // Bls base minus kv0, mi, i

  // ---- prologue: tile 0 ----
  {
    floatx4 sac[2][8] = {};
    bf16x8 kf0[8], kf1[8];
    LOAD_K(0, 0, kf0);
    QK_MFMA(0, kf0);
    LOAD_K(0, 1, kf1);
    QK_MFMA(1, kf1);
    LOAD_VH(0, vfA, 0);
    SOFTMAX_P(0);
    LOAD_VH(0, vfB, 2);
    PV_HALF(vfA, 0);
  }

  // ---- pipelined main loop ----
  for (int kv0 = 128; kv0 < S_LEN; kv0 += 128) {
    floatx4 sac[2][8] = {};
    bf16x8 kf0[8], kf1[8];
    LOAD_K(kv0, 0, kf0);   // K0 latency hides under PV_B(prev)
    PV_HALF(vfB, 2);       // consumes vfB(prev), Ps(prev) cols 64..127
    LOAD_K(kv0, 1, kf1);   // K1 latency hides under QK0
    QK_MFMA(0, kf0);
    QK_MFMA(1, kf1);
    LOAD_VH(kv0, vfA, 0);  // VA latency hides under softmax + P-store
    SOFTMAX_P(kv0);
    LOAD_VH(kv0, vfB, 2);  // VB latency hides under PV_A
    PV_HALF(vfA, 0);
  }

  // ---- epilogue: second PV half of last tile ----
  PV_HALF(vfB, 2);

  // one-time cross-lane l reduction (columns live on the 16 lanes of each quad)
  float linv[2][4];
#pragma unroll
  for (int mi = 0; mi < 2; ++mi)
#pragma unroll
    for (int i = 0; i < 4; ++i) {
      float ls = l_run[mi][i];
      ls += __shfl_xor(ls, 1);
      ls += __shfl_xor(ls, 2);
      ls += __shfl_xor(ls, 4);
      ls += __shfl_xor(ls, 8);
      linv[mi][i] = 1.f / ls;
    }

#pragma unroll
  for (int mi = 0; mi < 2; ++mi)
#pragma unroll
    for (int ni = 0; ni < 4; ++ni)
#pragma unroll
      for (int i = 0; i < 4; ++i) {
        float v = oacc[mi][ni][i] * linv[mi][i];
        int srow = q0 + wq + mi * 16 + quad * 4 + i;
        ctx[((size_t)(b * 2048 + srow)) * 1024 + h * 64 + ni * 16 + l16] = f2bf(v);
      }
}

extern "C" void kernel_launch(void* const* d_in, const int* in_sizes, int n_in,
                              void* d_out, int out_size, void* d_ws, size_t ws_size,
                              hipStream_t stream) {
  char* ws = (char*)d_ws;
  // R2/R6-proven workspace layout, byte-for-byte.
  unsigned short* Xbf  = (unsigned short*)(ws);                    // 8 MB
  unsigned short* Wcat = (unsigned short*)(ws + 8388608);          // 6 MB (Wq^T|Wk^T|Wv^T)
  unsigned short* Wto  = (unsigned short*)(ws + 14680064);         // 2 MB
  unsigned short* Qb   = (unsigned short*)(ws + 16777216);         // 8 MB  (K at +8MB, Vt at +16MB)
  unsigned short* ctx  = (unsigned short*)(ws + 41943040);         // 8 MB
  float*          bias = (float*)(ws + 50331648);                  // 16*4095*4
  int*            flag = (int*)(ws + 50593792);

  unsigned short* Kb  = Qb + 4194304;
  unsigned short* Vtb = Qb + 8388608;

  detect_k<<<1, 256, 0, stream>>>((const unsigned short*)d_in[0], flag);
  conv_x<<<2048, 256, 0, stream>>>(d_in[0], Xbf, flag, 524288);
  transpose_w<<<dim3(32, 32, 4), dim3(32, 8), 0, stream>>>(
      d_in[1], d_in[2], d_in[3], d_in[4], Wcat, Wto, flag);
  bias_k<<<256, 256, 0, stream>>>(d_in[5], bias, flag);

  // fused QKV GEMM: [4096,1024] @ [3072,1024]^T -> Q|K|Vt
  gemm_bt<<<dim3(24, 32), 256, 0, stream>>>(Xbf, Wcat, Qb, 0, flag);

  // flash attention: R0 shape (4 waves x 32 rows), spill-free pipeline
  attn_k<<<dim3(16, 32), 256, 0, stream>>>(Qb, Kb, Vtb, bias, ctx);

  // out GEMM: [4096,1024] @ [1024,1024]^T, 128x64 tiles
  gemm_out<<<dim3(16, 32), 256, 0, stream>>>(ctx, Wto, d_out, flag);
}

// Round 5
// 237.505 us; speedup vs baseline: 1.7156x; 1.2770x over previous
//
#include <hip/hip_runtime.h>
#include <math.h>

#define S_LEN 2048
#define DM 1024

typedef __attribute__((ext_vector_type(8))) __bf16 bf16x8;
typedef __attribute__((ext_vector_type(4))) float floatx4;

typedef __attribute__((address_space(1))) const unsigned int g_u32;
typedef __attribute__((address_space(3))) unsigned int l_u32;

__device__ __forceinline__ unsigned short f2bf(float f) {
  union { float f; unsigned int u; } v; v.f = f;
  return (unsigned short)((v.u + 0x7fffu + ((v.u >> 16) & 1u)) >> 16);
}
__device__ __forceinline__ float bf2f(unsigned short u) {
  union { unsigned int u; float f; } v; v.u = ((unsigned int)u) << 16;
  return v.f;
}
__device__ __forceinline__ bf16x8 ld_frag(const unsigned short* p) {
  union { uint4 u; bf16x8 v; } t;
  t.u = *(const uint4*)p;
  return t.v;
}

// ---------------- dtype probe: 1 = buffers are fp32, 0 = bf16 ----------------
__global__ void detect_k(const unsigned short* __restrict__ x, int* __restrict__ flag) {
  __shared__ int cnt;
  if (threadIdx.x == 0) cnt = 0;
  __syncthreads();
  int local = 0;
  for (int i = threadIdx.x; i < 4096; i += 256) {
    unsigned short u = x[i];
    int e = (u >> 7) & 0xFF;
    if (e > 140) local++;
  }
  atomicAdd(&cnt, local);
  __syncthreads();
  if (threadIdx.x == 0) *flag = (cnt > 64) ? 1 : 0;
}

// ---------------- convert hidden_states to bf16 (8 elems/thread) ----------------
__global__ void conv_x(const void* __restrict__ src, unsigned short* __restrict__ dst,
                       const int* __restrict__ flag, int n8) {
  int i = blockIdx.x * 256 + threadIdx.x;
  if (i >= n8) return;
  if (*flag) {
    const float4* s = (const float4*)src;
    float4 a = s[2 * i], b = s[2 * i + 1];
    union { uint4 u4; unsigned short s[8]; } o;
    o.s[0] = f2bf(a.x); o.s[1] = f2bf(a.y); o.s[2] = f2bf(a.z); o.s[3] = f2bf(a.w);
    o.s[4] = f2bf(b.x); o.s[5] = f2bf(b.y); o.s[6] = f2bf(b.z); o.s[7] = f2bf(b.w);
    ((uint4*)dst)[i] = o.u4;
  } else {
    ((uint4*)dst)[i] = ((const uint4*)src)[i];
  }
}

// ---------------- transpose 1024x1024 weights -> bf16 W^T (4 mats, one launch) ----------------
__global__ void transpose_w(const void* __restrict__ s0, const void* __restrict__ s1,
                            const void* __restrict__ s2, const void* __restrict__ s3,
                            unsigned short* __restrict__ Wcat, unsigned short* __restrict__ Wto,
                            const int* __restrict__ flag) {
  __shared__ float tile[32][33];
  const int z = blockIdx.z;
  const void* src = (z == 0) ? s0 : (z == 1) ? s1 : (z == 2) ? s2 : s3;
  unsigned short* dst = (z < 3) ? (Wcat + (size_t)z * 1048576) : Wto;
  const int isf = *flag;
  int x = blockIdx.x * 32 + threadIdx.x;
  int y0 = blockIdx.y * 32;
  for (int i = threadIdx.y; i < 32; i += 8) {
    float v;
    if (isf) v = ((const float*)src)[(size_t)(y0 + i) * DM + x];
    else     v = bf2f(((const unsigned short*)src)[(size_t)(y0 + i) * DM + x]);
    tile[i][threadIdx.x] = v;
  }
  __syncthreads();
  int xo = y0 + threadIdx.x;
  for (int i = threadIdx.y; i < 32; i += 8)
    dst[(size_t)(blockIdx.x * 32 + i) * DM + xo] = f2bf(tile[threadIdx.x][i]);
}

// ---------------- dense relative-position bias table [16][4095] ----------------
__global__ void bias_k(const void* __restrict__ table, float* __restrict__ out,
                       const int* __restrict__ flag) {
  int idx = blockIdx.x * 256 + threadIdx.x;
  if (idx >= 16 * 4095) return;
  int h = idx / 4095;
  int j = idx - h * 4095;
  int delta = j - 2047;            // k - q
  int bucket = (delta > 0) ? 16 : 0;
  int ad = (delta < 0) ? -delta : delta;
  int smallv;
  if (ad < 8) smallv = ad;
  else {
    int l = (int)(log((double)ad * 0.125) * (8.0 / log(16.0)));
    smallv = 8 + l;
    if (smallv > 15) smallv = 15;
  }
  bucket += smallv;
  float v;
  if (*flag) v = ((const float*)table)[bucket * 16 + h];
  else       v = bf2f(((const unsigned short*)table)[bucket * 16 + h]);
  out[idx] = v;
}

// ---------------- bf16 GEMM, m97-style (global_load_lds, unpadded LDS) ----------------
// mode 0: fused QKV, N=3072, C = Qb base (Q|K|V contiguous, V transposed)
__global__ __launch_bounds__(256) void gemm_bt(
    const unsigned short* __restrict__ A, const unsigned short* __restrict__ Bt,
    void* __restrict__ C, int mode, const int* __restrict__ flag)
{
  __shared__ __align__(16) unsigned short As[128 * 64];
  __shared__ __align__(16) unsigned short Bs[128 * 64];
  const int tid = threadIdx.x;
  const int lane = tid & 63, wave = tid >> 6;
  const int l16 = lane & 15, quad = lane >> 4;
  const int wm = (wave >> 1) << 6, wn = (wave & 1) << 6;
  const int m0 = blockIdx.y << 7, n0 = blockIdx.x << 7;
  const int lrow = lane >> 3, lcol = (lane & 7) << 3;

  floatx4 acc[4][4] = {};

  for (int k0 = 0; k0 < 1024; k0 += 64) {
    __syncthreads();
#pragma unroll
    for (int i = 0; i < 4; ++i) {
      int r0 = wave * 32 + i * 8;
      __builtin_amdgcn_global_load_lds(
          (g_u32*)(const void*)(A + (size_t)(m0 + r0 + lrow) * 1024 + k0 + lcol),
          (l_u32*)(void*)&As[r0 * 64], 16, 0, 0);
      __builtin_amdgcn_global_load_lds(
          (g_u32*)(const void*)(Bt + (size_t)(n0 + r0 + lrow) * 1024 + k0 + lcol),
          (l_u32*)(void*)&Bs[r0 * 64], 16, 0, 0);
    }
    __syncthreads();
#pragma unroll
    for (int ks = 0; ks < 2; ++ks) {
      bf16x8 a[4], b[4];
#pragma unroll
      for (int mi = 0; mi < 4; ++mi)
        a[mi] = *(const bf16x8*)&As[(wm + mi * 16 + l16) * 64 + ks * 32 + quad * 8];
#pragma unroll
      for (int ni = 0; ni < 4; ++ni)
        b[ni] = *(const bf16x8*)&Bs[(wn + ni * 16 + l16) * 64 + ks * 32 + quad * 8];
#pragma unroll
      for (int mi = 0; mi < 4; ++mi)
#pragma unroll
        for (int ni = 0; ni < 4; ++ni)
          acc[mi][ni] = __builtin_amdgcn_mfma_f32_16x16x32_bf16(a[mi], b[ni], acc[mi][ni], 0, 0, 0);
    }
  }

  if (mode == 0) {
    unsigned short* Cs = (unsigned short*)C;
    const int mat = n0 >> 10;           // uniform per block
#pragma unroll
    for (int mi = 0; mi < 4; ++mi)
#pragma unroll
      for (int ni = 0; ni < 4; ++ni)
#pragma unroll
        for (int i = 0; i < 4; ++i) {
          int m = m0 + wm + mi * 16 + quad * 4 + i;
          int n = (n0 & 1023) + wn + ni * 16 + l16;
          int b = m >> 11, s = m & 2047, h = n >> 6, d = n & 63;
          unsigned short v = f2bf(acc[mi][ni][i]);
          if (mat < 2)
            Cs[(size_t)mat * 4194304 + (((size_t)(b * 16 + h)) * 2048 + s) * 64 + d] = v;
          else
            Cs[(size_t)2 * 4194304 + (((size_t)(b * 16 + h)) * 64 + d) * 2048 + s] = v;
        }
  } else {
    const int isf = *flag;
#pragma unroll
    for (int mi = 0; mi < 4; ++mi)
#pragma unroll
      for (int ni = 0; ni < 4; ++ni)
#pragma unroll
        for (int i = 0; i < 4; ++i) {
          int m = m0 + wm + mi * 16 + quad * 4 + i;
          int n = n0 + wn + ni * 16 + l16;
          size_t idx = (size_t)m * 1024 + n;
          float v = acc[mi][ni][i];
          if (isf) ((float*)C)[idx] = v;
          else     ((unsigned short*)C)[idx] = f2bf(v);
        }
  }
}

// ---------------- out GEMM, 128x64 tiles (512 blocks = 2/CU) ----------------
__global__ __launch_bounds__(256) void gemm_out(
    const unsigned short* __restrict__ A, const unsigned short* __restrict__ Bt,
    void* __restrict__ C, const int* __restrict__ flag)
{
  __shared__ __align__(16) unsigned short As[128 * 64];
  __shared__ __align__(16) unsigned short Bs[64 * 64];
  const int tid = threadIdx.x;
  const int lane = tid & 63, wave = tid >> 6;
  const int l16 = lane & 15, quad = lane >> 4;
  const int wm = (wave >> 1) << 6, wn = (wave & 1) << 5;
  const int m0 = blockIdx.y << 7, n0 = blockIdx.x << 6;
  const int lrow = lane >> 3, lcol = (lane & 7) << 3;

  floatx4 acc[4][2] = {};

  for (int k0 = 0; k0 < 1024; k0 += 64) {
    __syncthreads();
#pragma unroll
    for (int i = 0; i < 4; ++i) {
      int r0 = wave * 32 + i * 8;
      __builtin_amdgcn_global_load_lds(
          (g_u32*)(const void*)(A + (size_t)(m0 + r0 + lrow) * 1024 + k0 + lcol),
          (l_u32*)(void*)&As[r0 * 64], 16, 0, 0);
    }
#pragma unroll
    for (int i = 0; i < 2; ++i) {
      int r0 = wave * 16 + i * 8;
      __builtin_amdgcn_global_load_lds(
          (g_u32*)(const void*)(Bt + (size_t)(n0 + r0 + lrow) * 1024 + k0 + lcol),
          (l_u32*)(void*)&Bs[r0 * 64], 16, 0, 0);
    }
    __syncthreads();
#pragma unroll
    for (int ks = 0; ks < 2; ++ks) {
      bf16x8 a[4], b[2];
#pragma unroll
      for (int mi = 0; mi < 4; ++mi)
        a[mi] = *(const bf16x8*)&As[(wm + mi * 16 + l16) * 64 + ks * 32 + quad * 8];
#pragma unroll
      for (int ni = 0; ni < 2; ++ni)
        b[ni] = *(const bf16x8*)&Bs[(wn + ni * 16 + l16) * 64 + ks * 32 + quad * 8];
#pragma unroll
      for (int mi = 0; mi < 4; ++mi)
#pragma unroll
        for (int ni = 0; ni < 2; ++ni)
          acc[mi][ni] = __builtin_amdgcn_mfma_f32_16x16x32_bf16(a[mi], b[ni], acc[mi][ni], 0, 0, 0);
    }
  }

  const int isf = *flag;
#pragma unroll
  for (int mi = 0; mi < 4; ++mi)
#pragma unroll
    for (int ni = 0; ni < 2; ++ni)
#pragma unroll
      for (int i = 0; i < 4; ++i) {
        int m = m0 + wm + mi * 16 + quad * 4 + i;
        int n = n0 + wn + ni * 16 + l16;
        size_t idx = (size_t)m * 1024 + n;
        float v = acc[mi][ni][i];
        if (isf) ((float*)C)[idx] = v;
        else     ((unsigned short*)C)[idx] = f2bf(v);
      }
}

// ---------------- flash attention: block-shared LDS-staged K/V (m97 pattern) ----------------
// 4 waves x 32 q-rows, grid (16,32). R0-R4 lesson: per-wave register loads of
// K/V are 4x redundant (all waves read the same tiles) and their latency can't
// be pipelined from HIP source. Fix: cooperative global_load_lds staging of
// K[128][64] and V[64][128] per tile, barrier-synced, single-buffered -- the
// structure that gives the GEMMs here 37% MfmaUtil. XOR-swizzle applied
// BOTH-SIDES (pre-swizzled global source + swizzled ds_read, rule #21):
//   K: lds[r][s] holds K[r][(s^(r&7))*8..]   (8x16B slots per 128B row)
//   V: lds[d][s] holds V[d][(s^(d&15))*8..]  (16x16B slots per 256B row)
// -> every fragment ds_read_b128 is bank-balanced (8 lanes/slot).
// Bias windowed to 2175 entries (q-block span) so LDS = 34.8+16+16+8.7 = 76.3KB
// -> 2 blocks/CU.
#define STAGE_KV(kv0)                                                          \
  _Pragma("unroll")                                                           \
  for (int i = 0; i < 4; ++i) {                                               \
    int kr = i * 32 + wave * 8 + (lane >> 3);                                 \
    __builtin_amdgcn_global_load_lds(                                         \
        (g_u32*)(const void*)(Kp + (size_t)((kv0) + kr) * 64 +                \
                              (((lane & 7) ^ (lane >> 3)) << 3)),             \
        (l_u32*)(void*)&Ks[i * 2048 + wave * 512], 16, 0, 0);                 \
    int vd = i * 16 + wave * 4 + (lane >> 4);                                 \
    __builtin_amdgcn_global_load_lds(                                         \
        (g_u32*)(const void*)(Vp + (size_t)vd * S_LEN + (kv0) +               \
                              (((lane & 15) ^ (wave * 4 + (lane >> 4))) << 3)),\
        (l_u32*)(void*)&Vs[i * 2048 + wave * 512], 16, 0, 0);                 \
  }

__global__ __launch_bounds__(256, 2) void attn_k(
    const unsigned short* __restrict__ Q, const unsigned short* __restrict__ K,
    const unsigned short* __restrict__ Vt, const float* __restrict__ bias,
    unsigned short* __restrict__ ctx)
{
  __shared__ __align__(16) unsigned short Ks[128 * 64];    // 16 KB, swizzled
  __shared__ __align__(16) unsigned short Vs[64 * 128];    // 16 KB, swizzled
  __shared__ __align__(16) unsigned short Ps[4][32][136];  // wave-private, padded
  __shared__ float Bls[2176];   // windowed bias*log2e-24: Bls[i] = b(i-(q0+127))
  const int tid = threadIdx.x;
  const int lane = tid & 63, wave = tid >> 6;
  const int l16 = lane & 15, quad = lane >> 4;
  const int bh = blockIdx.y;
  const int b = bh >> 4, h = bh & 15;
  const int q0 = blockIdx.x << 7;
  const int wq = wave << 5;

  const unsigned short* Qp = Q + (size_t)bh * S_LEN * 64;
  const unsigned short* Kp = K + (size_t)bh * S_LEN * 64;
  const unsigned short* Vp = Vt + (size_t)bh * 64 * S_LEN;
  const float* biasg = bias + h * 4095 + (1920 - q0);  // window base: delta = -(q0+127)

  // stage tile 0 + bias window + Q fragments before the first barrier
  STAGE_KV(0);
  for (int i = tid; i < 2175; i += 256)
    Bls[i] = fmaf(biasg[i], 1.44269504f, -24.f);

  bf16x8 qf[2][2];
#pragma unroll
  for (int mi = 0; mi < 2; ++mi)
#pragma unroll
    for (int ks = 0; ks < 2; ++ks)
      qf[mi][ks] = ld_frag(Qp + (size_t)(q0 + wq + mi * 16 + l16) * 64 + ks * 32 + quad * 8);

  float l_run[2][4] = {};
  floatx4 oacc[2][4] = {};

  const int qwb = q0 + wq;                          // wave's first q row
  const int rbase = 127 + l16 - wq - (quad << 2);   // Bls idx base minus kv0, mi, i

  __syncthreads();  // staging of tile 0 + bias visible

  for (int kv0 = 0; kv0 < S_LEN; kv0 += 128) {
    const float Bneg = Bls[0], Bpos = Bls[2174];

    // ---- QK^T from swizzled LDS K ----
    floatx4 sac[2][8] = {};
#pragma unroll
    for (int ks = 0; ks < 2; ++ks) {
      bf16x8 kf[8];
#pragma unroll
      for (int ni = 0; ni < 8; ++ni)
        kf[ni] = *(const bf16x8*)&Ks[(ni * 16 + l16) * 64 +
                                     ((((ks << 2) + quad) ^ (l16 & 7)) << 3)];
#pragma unroll
      for (int mi = 0; mi < 2; ++mi)
#pragma unroll
        for (int ni = 0; ni < 8; ++ni)
          sac[mi][ni] = __builtin_amdgcn_mfma_f32_16x16x32_bf16(qf[mi][ks], kf[ni], sac[mi][ni], 0, 0, 0);
    }

    // ---- fixed-max softmax (saturated-bucket fast path) ----
    {
      const int dmin = kv0 - (qwb + 31);
      const int dmax = kv0 + 127 - qwb;
      if (dmin >= 96 || dmax <= -96) {
        const float bc = (dmin >= 96) ? Bpos : Bneg;
#pragma unroll
        for (int mi = 0; mi < 2; ++mi)
#pragma unroll
          for (int i = 0; i < 4; ++i) {
            float sum = 0.f;
#pragma unroll
            for (int ni = 0; ni < 8; ++ni) {
              float e = __builtin_amdgcn_exp2f(fmaf(sac[mi][ni][i], 1.44269504f, bc));
              sac[mi][ni][i] = e; sum += e;
            }
            l_run[mi][i] += sum;
          }
      } else {
#pragma unroll
        for (int mi = 0; mi < 2; ++mi)
#pragma unroll
          for (int i = 0; i < 4; ++i) {
            const int bbase = kv0 + rbase - i - mi * 16;
            float sum = 0.f;
#pragma unroll
            for (int ni = 0; ni < 8; ++ni) {
              float e = __builtin_amdgcn_exp2f(
                  fmaf(sac[mi][ni][i], 1.44269504f, Bls[bbase + ni * 16]));
              sac[mi][ni][i] = e; sum += e;
            }
            l_run[mi][i] += sum;
          }
      }
    }

    // ---- P -> LDS (wave-private, no barrier) ----
#pragma unroll
    for (int mi = 0; mi < 2; ++mi)
#pragma unroll
      for (int ni = 0; ni < 8; ++ni)
#pragma unroll
        for (int i = 0; i < 4; ++i)
          Ps[wave][mi * 16 + quad * 4 + i][ni * 16 + l16] = f2bf(sac[mi][ni][i]);

    // ---- PV from swizzled LDS V ----
#pragma unroll
    for (int ks2 = 0; ks2 < 4; ++ks2) {
      bf16x8 af[2], vf[4];
#pragma unroll
      for (int mi = 0; mi < 2; ++mi)
        af[mi] = *(const bf16x8*)&Ps[wave][mi * 16 + l16][ks2 * 32 + quad * 8];
#pragma unroll
      for (int ni = 0; ni < 4; ++ni)
        vf[ni] = *(const bf16x8*)&Vs[(ni * 16 + l16) * 128 +
                                     ((((ks2 << 2) + quad) ^ l16) << 3)];
#pragma unroll
      for (int mi = 0; mi < 2; ++mi)
#pragma unroll
        for (int ni = 0; ni < 4; ++ni)
          oacc[mi][ni] = __builtin_amdgcn_mfma_f32_16x16x32_bf16(af[mi], vf[ni], oacc[mi][ni], 0, 0, 0);
    }

    // ---- stage next tile ----
    if (kv0 + 128 < S_LEN) {
      __syncthreads();          // all waves done reading Ks/Vs
      STAGE_KV(kv0 + 128);
      __syncthreads();          // staging drained (vmcnt0 before barrier)
    }
  }

  // one-time cross-lane l reduction (columns live on the 16 lanes of each quad)
  float linv[2][4];
#pragma unroll
  for (int mi = 0; mi < 2; ++mi)
#pragma unroll
    for (int i = 0; i < 4; ++i) {
      float ls = l_run[mi][i];
      ls += __shfl_xor(ls, 1);
      ls += __shfl_xor(ls, 2);
      ls += __shfl_xor(ls, 4);
      ls += __shfl_xor(ls, 8);
      linv[mi][i] = 1.f / ls;
    }

#pragma unroll
  for (int mi = 0; mi < 2; ++mi)
#pragma unroll
    for (int ni = 0; ni < 4; ++ni)
#pragma unroll
      for (int i = 0; i < 4; ++i) {
        float v = oacc[mi][ni][i] * linv[mi][i];
        int srow = q0 + wq + mi * 16 + quad * 4 + i;
        ctx[((size_t)(b * 2048 + srow)) * 1024 + h * 64 + ni * 16 + l16] = f2bf(v);
      }
}

extern "C" void kernel_launch(void* const* d_in, const int* in_sizes, int n_in,
                              void* d_out, int out_size, void* d_ws, size_t ws_size,
                              hipStream_t stream) {
  char* ws = (char*)d_ws;
  // R2/R6-proven workspace layout, byte-for-byte.
  unsigned short* Xbf  = (unsigned short*)(ws);                    // 8 MB
  unsigned short* Wcat = (unsigned short*)(ws + 8388608);          // 6 MB (Wq^T|Wk^T|Wv^T)
  unsigned short* Wto  = (unsigned short*)(ws + 14680064);         // 2 MB
  unsigned short* Qb   = (unsigned short*)(ws + 16777216);         // 8 MB  (K at +8MB, Vt at +16MB)
  unsigned short* ctx  = (unsigned short*)(ws + 41943040);         // 8 MB
  float*          bias = (float*)(ws + 50331648);                  // 16*4095*4
  int*            flag = (int*)(ws + 50593792);

  unsigned short* Kb  = Qb + 4194304;
  unsigned short* Vtb = Qb + 8388608;

  detect_k<<<1, 256, 0, stream>>>((const unsigned short*)d_in[0], flag);
  conv_x<<<2048, 256, 0, stream>>>(d_in[0], Xbf, flag, 524288);
  transpose_w<<<dim3(32, 32, 4), dim3(32, 8), 0, stream>>>(
      d_in[1], d_in[2], d_in[3], d_in[4], Wcat, Wto, flag);
  bias_k<<<256, 256, 0, stream>>>(d_in[5], bias, flag);

  // fused QKV GEMM: [4096,1024] @ [3072,1024]^T -> Q|K|Vt
  gemm_bt<<<dim3(24, 32), 256, 0, stream>>>(Xbf, Wcat, Qb, 0, flag);

  // flash attention: block-shared LDS-staged K/V, XOR-swizzled
  attn_k<<<dim3(16, 32), 256, 0, stream>>>(Qb, Kb, Vtb, bias, ctx);

  // out GEMM: [4096,1024] @ [1024,1024]^T, 128x64 tiles
  gemm_out<<<dim3(16, 32), 256, 0, stream>>>(ctx, Wto, d_out, flag);
}

// Round 6
// 230.932 us; speedup vs baseline: 1.7644x; 1.0285x over previous
//
#include <hip/hip_runtime.h>
#include <math.h>

#define S_LEN 2048
#define DM 1024

typedef __attribute__((ext_vector_type(8))) __bf16 bf16x8;
typedef __attribute__((ext_vector_type(4))) float floatx4;

typedef __attribute__((address_space(1))) const unsigned int g_u32;
typedef __attribute__((address_space(3))) unsigned int l_u32;

__device__ __forceinline__ unsigned short f2bf(float f) {
  union { float f; unsigned int u; } v; v.f = f;
  return (unsigned short)((v.u + 0x7fffu + ((v.u >> 16) & 1u)) >> 16);
}
__device__ __forceinline__ float bf2f(unsigned short u) {
  union { unsigned int u; float f; } v; v.u = ((unsigned int)u) << 16;
  return v.f;
}
__device__ __forceinline__ bf16x8 ld_frag(const unsigned short* p) {
  union { uint4 u; bf16x8 v; } t;
  t.u = *(const uint4*)p;
  return t.v;
}

// ---------------- dtype probe: 1 = buffers are fp32, 0 = bf16 ----------------
__global__ void detect_k(const unsigned short* __restrict__ x, int* __restrict__ flag) {
  __shared__ int cnt;
  if (threadIdx.x == 0) cnt = 0;
  __syncthreads();
  int local = 0;
  for (int i = threadIdx.x; i < 4096; i += 256) {
    unsigned short u = x[i];
    int e = (u >> 7) & 0xFF;
    if (e > 140) local++;
  }
  atomicAdd(&cnt, local);
  __syncthreads();
  if (threadIdx.x == 0) *flag = (cnt > 64) ? 1 : 0;
}

// ---------------- convert hidden_states to bf16 (8 elems/thread) ----------------
__global__ void conv_x(const void* __restrict__ src, unsigned short* __restrict__ dst,
                       const int* __restrict__ flag, int n8) {
  int i = blockIdx.x * 256 + threadIdx.x;
  if (i >= n8) return;
  if (*flag) {
    const float4* s = (const float4*)src;
    float4 a = s[2 * i], b = s[2 * i + 1];
    union { uint4 u4; unsigned short s[8]; } o;
    o.s[0] = f2bf(a.x); o.s[1] = f2bf(a.y); o.s[2] = f2bf(a.z); o.s[3] = f2bf(a.w);
    o.s[4] = f2bf(b.x); o.s[5] = f2bf(b.y); o.s[6] = f2bf(b.z); o.s[7] = f2bf(b.w);
    ((uint4*)dst)[i] = o.u4;
  } else {
    ((uint4*)dst)[i] = ((const uint4*)src)[i];
  }
}

// ---------------- transpose 1024x1024 weights -> bf16 W^T (4 mats, one launch) ----------------
__global__ void transpose_w(const void* __restrict__ s0, const void* __restrict__ s1,
                            const void* __restrict__ s2, const void* __restrict__ s3,
                            unsigned short* __restrict__ Wcat, unsigned short* __restrict__ Wto,
                            const int* __restrict__ flag) {
  __shared__ float tile[32][33];
  const int z = blockIdx.z;
  const void* src = (z == 0) ? s0 : (z == 1) ? s1 : (z == 2) ? s2 : s3;
  unsigned short* dst = (z < 3) ? (Wcat + (size_t)z * 1048576) : Wto;
  const int isf = *flag;
  int x = blockIdx.x * 32 + threadIdx.x;
  int y0 = blockIdx.y * 32;
  for (int i = threadIdx.y; i < 32; i += 8) {
    float v;
    if (isf) v = ((const float*)src)[(size_t)(y0 + i) * DM + x];
    else     v = bf2f(((const unsigned short*)src)[(size_t)(y0 + i) * DM + x]);
    tile[i][threadIdx.x] = v;
  }
  __syncthreads();
  int xo = y0 + threadIdx.x;
  for (int i = threadIdx.y; i < 32; i += 8)
    dst[(size_t)(blockIdx.x * 32 + i) * DM + xo] = f2bf(tile[threadIdx.x][i]);
}

// ---------------- dense relative-position bias table [16][4095] ----------------
__global__ void bias_k(const void* __restrict__ table, float* __restrict__ out,
                       const int* __restrict__ flag) {
  int idx = blockIdx.x * 256 + threadIdx.x;
  if (idx >= 16 * 4095) return;
  int h = idx / 4095;
  int j = idx - h * 4095;
  int delta = j - 2047;            // k - q
  int bucket = (delta > 0) ? 16 : 0;
  int ad = (delta < 0) ? -delta : delta;
  int smallv;
  if (ad < 8) smallv = ad;
  else {
    int l = (int)(log((double)ad * 0.125) * (8.0 / log(16.0)));
    smallv = 8 + l;
    if (smallv > 15) smallv = 15;
  }
  bucket += smallv;
  float v;
  if (*flag) v = ((const float*)table)[bucket * 16 + h];
  else       v = bf2f(((const unsigned short*)table)[bucket * 16 + h]);
  out[idx] = v;
}

// ---------------- bf16 GEMM, m97-style (global_load_lds, unpadded LDS) ----------------
// mode 0: fused QKV, N=3072, C = Qb base (Q|K|V contiguous, V transposed)
// V^T epilogue (mat==2) now goes through an LDS transpose (aliased over As/Bs,
// stride 136 shorts so rows stay 16B-aligned) -> coalesced 16B stores. The old
// path scattered 64 x 2B stores/thread at 4KB stride (64 cache lines per wave
// store instruction).
__global__ __launch_bounds__(256) void gemm_bt(
    const unsigned short* __restrict__ A, const unsigned short* __restrict__ Bt,
    void* __restrict__ C, int mode, const int* __restrict__ flag)
{
  __shared__ __align__(16) unsigned short smem[128 * 136];  // 34816 B; As|Bs alias + T
  unsigned short* As = smem;          // 128*64
  unsigned short* Bs = smem + 8192;   // 128*64
  const int tid = threadIdx.x;
  const int lane = tid & 63, wave = tid >> 6;
  const int l16 = lane & 15, quad = lane >> 4;
  const int wm = (wave >> 1) << 6, wn = (wave & 1) << 6;
  const int m0 = blockIdx.y << 7, n0 = blockIdx.x << 7;
  const int lrow = lane >> 3, lcol = (lane & 7) << 3;

  floatx4 acc[4][4] = {};

  for (int k0 = 0; k0 < 1024; k0 += 64) {
    __syncthreads();
#pragma unroll
    for (int i = 0; i < 4; ++i) {
      int r0 = wave * 32 + i * 8;
      __builtin_amdgcn_global_load_lds(
          (g_u32*)(const void*)(A + (size_t)(m0 + r0 + lrow) * 1024 + k0 + lcol),
          (l_u32*)(void*)&As[r0 * 64], 16, 0, 0);
      __builtin_amdgcn_global_load_lds(
          (g_u32*)(const void*)(Bt + (size_t)(n0 + r0 + lrow) * 1024 + k0 + lcol),
          (l_u32*)(void*)&Bs[r0 * 64], 16, 0, 0);
    }
    __syncthreads();
#pragma unroll
    for (int ks = 0; ks < 2; ++ks) {
      bf16x8 a[4], b[4];
#pragma unroll
      for (int mi = 0; mi < 4; ++mi)
        a[mi] = *(const bf16x8*)&As[(wm + mi * 16 + l16) * 64 + ks * 32 + quad * 8];
#pragma unroll
      for (int ni = 0; ni < 4; ++ni)
        b[ni] = *(const bf16x8*)&Bs[(wn + ni * 16 + l16) * 64 + ks * 32 + quad * 8];
#pragma unroll
      for (int mi = 0; mi < 4; ++mi)
#pragma unroll
        for (int ni = 0; ni < 4; ++ni)
          acc[mi][ni] = __builtin_amdgcn_mfma_f32_16x16x32_bf16(a[mi], b[ni], acc[mi][ni], 0, 0, 0);
    }
  }

  if (mode == 0) {
    unsigned short* Cs = (unsigned short*)C;
    const int mat = n0 >> 10;           // uniform per block
    if (mat < 2) {
#pragma unroll
      for (int mi = 0; mi < 4; ++mi)
#pragma unroll
        for (int ni = 0; ni < 4; ++ni)
#pragma unroll
          for (int i = 0; i < 4; ++i) {
            int m = m0 + wm + mi * 16 + quad * 4 + i;
            int n = (n0 & 1023) + wn + ni * 16 + l16;
            int b = m >> 11, s = m & 2047, h = n >> 6, d = n & 63;
            Cs[(size_t)mat * 4194304 + (((size_t)(b * 16 + h)) * 2048 + s) * 64 + d] =
                f2bf(acc[mi][ni][i]);
          }
    } else {
      // V^T via LDS transpose: T[n][m] then coalesced rows of V^T
      __syncthreads();  // all waves done with As/Bs
#pragma unroll
      for (int mi = 0; mi < 4; ++mi)
#pragma unroll
        for (int ni = 0; ni < 4; ++ni) {
          union { unsigned short s[4]; uint2 u; } w;
#pragma unroll
          for (int i = 0; i < 4; ++i) w.s[i] = f2bf(acc[mi][ni][i]);
          *(uint2*)&smem[(wn + ni * 16 + l16) * 136 + wm + mi * 16 + quad * 4] = w.u;
        }
      __syncthreads();
      const int bb = m0 >> 11, s0 = m0 & 2047, nb = n0 & 1023;
#pragma unroll
      for (int it = 0; it < 8; ++it) {
        int r = it * 16 + (tid >> 4);
        int c = (tid & 15) * 8;
        uint4 rv = *(const uint4*)&smem[r * 136 + c];
        *(uint4*)&Cs[(size_t)2 * 4194304 + (size_t)(bb * 1024 + nb + r) * 2048 + s0 + c] = rv;
      }
    }
  } else {
    const int isf = *flag;
#pragma unroll
    for (int mi = 0; mi < 4; ++mi)
#pragma unroll
      for (int ni = 0; ni < 4; ++ni)
#pragma unroll
        for (int i = 0; i < 4; ++i) {
          int m = m0 + wm + mi * 16 + quad * 4 + i;
          int n = n0 + wn + ni * 16 + l16;
          size_t idx = (size_t)m * 1024 + n;
          float v = acc[mi][ni][i];
          if (isf) ((float*)C)[idx] = v;
          else     ((unsigned short*)C)[idx] = f2bf(v);
        }
  }
}

// ---------------- out GEMM, 128x64 tiles (512 blocks = 2/CU) ----------------
__global__ __launch_bounds__(256) void gemm_out(
    const unsigned short* __restrict__ A, const unsigned short* __restrict__ Bt,
    void* __restrict__ C, const int* __restrict__ flag)
{
  __shared__ __align__(16) unsigned short As[128 * 64];
  __shared__ __align__(16) unsigned short Bs[64 * 64];
  const int tid = threadIdx.x;
  const int lane = tid & 63, wave = tid >> 6;
  const int l16 = lane & 15, quad = lane >> 4;
  const int wm = (wave >> 1) << 6, wn = (wave & 1) << 5;
  const int m0 = blockIdx.y << 7, n0 = blockIdx.x << 6;
  const int lrow = lane >> 3, lcol = (lane & 7) << 3;

  floatx4 acc[4][2] = {};

  for (int k0 = 0; k0 < 1024; k0 += 64) {
    __syncthreads();
#pragma unroll
    for (int i = 0; i < 4; ++i) {
      int r0 = wave * 32 + i * 8;
      __builtin_amdgcn_global_load_lds(
          (g_u32*)(const void*)(A + (size_t)(m0 + r0 + lrow) * 1024 + k0 + lcol),
          (l_u32*)(void*)&As[r0 * 64], 16, 0, 0);
    }
#pragma unroll
    for (int i = 0; i < 2; ++i) {
      int r0 = wave * 16 + i * 8;
      __builtin_amdgcn_global_load_lds(
          (g_u32*)(const void*)(Bt + (size_t)(n0 + r0 + lrow) * 1024 + k0 + lcol),
          (l_u32*)(void*)&Bs[r0 * 64], 16, 0, 0);
    }
    __syncthreads();
#pragma unroll
    for (int ks = 0; ks < 2; ++ks) {
      bf16x8 a[4], b[2];
#pragma unroll
      for (int mi = 0; mi < 4; ++mi)
        a[mi] = *(const bf16x8*)&As[(wm + mi * 16 + l16) * 64 + ks * 32 + quad * 8];
#pragma unroll
      for (int ni = 0; ni < 2; ++ni)
        b[ni] = *(const bf16x8*)&Bs[(wn + ni * 16 + l16) * 64 + ks * 32 + quad * 8];
#pragma unroll
      for (int mi = 0; mi < 4; ++mi)
#pragma unroll
        for (int ni = 0; ni < 2; ++ni)
          acc[mi][ni] = __builtin_amdgcn_mfma_f32_16x16x32_bf16(a[mi], b[ni], acc[mi][ni], 0, 0, 0);
    }
  }

  const int isf = *flag;
#pragma unroll
  for (int mi = 0; mi < 4; ++mi)
#pragma unroll
    for (int ni = 0; ni < 2; ++ni)
#pragma unroll
      for (int i = 0; i < 4; ++i) {
        int m = m0 + wm + mi * 16 + quad * 4 + i;
        int n = n0 + wn + ni * 16 + l16;
        size_t idx = (size_t)m * 1024 + n;
        float v = acc[mi][ni][i];
        if (isf) ((float*)C)[idx] = v;
        else     ((unsigned short*)C)[idx] = f2bf(v);
      }
}

// ---------------- flash attention: double-buffered LDS K/V, KVBLK=64 ----------------
// R5 (single-buffered, KVBLK=128) = 79.7us: sync -> STAGE -> sync(vmcnt0) still
// serializes a full HBM round-trip per tile. Now: 2 buffers, stage tile t+1
// BEFORE computing tile t, ONE barrier per tile -- staging latency hides under
// the whole tile's MFMA+softmax. LDS 59.9 KB -> still 2 blocks/CU.
// Swizzle (both-sides, rule #21): lds[r][s] = X[r][s ^ (r&7)] for 8x16B rows.
#define STAGE_KV(kv0, buf)                                                    \
  _Pragma("unroll")                                                           \
  for (int i = 0; i < 2; ++i) {                                               \
    int rr = i * 32 + wave * 8 + (lane >> 3);                                 \
    int sw = ((lane & 7) ^ (lane >> 3)) << 3;                                 \
    __builtin_amdgcn_global_load_lds(                                         \
        (g_u32*)(const void*)(Kp + (size_t)((kv0) + rr) * 64 + sw),           \
        (l_u32*)(void*)&Ks[buf][i * 2048 + wave * 512], 16, 0, 0);            \
    __builtin_amdgcn_global_load_lds(                                         \
        (g_u32*)(const void*)(Vp + (size_t)rr * S_LEN + (kv0) + sw),          \
        (l_u32*)(void*)&Vs[buf][i * 2048 + wave * 512], 16, 0, 0);            \
  }

__global__ __launch_bounds__(256, 2) void attn_k(
    const unsigned short* __restrict__ Q, const unsigned short* __restrict__ K,
    const unsigned short* __restrict__ Vt, const float* __restrict__ bias,
    unsigned short* __restrict__ ctx)
{
  __shared__ __align__(16) unsigned short Ks[2][4096];     // K [64][64] x2, swizzled
  __shared__ __align__(16) unsigned short Vs[2][4096];     // V^T [64d][64kv] x2, swizzled
  __shared__ __align__(16) unsigned short Ps[4][32][72];   // wave-private, padded
  __shared__ float Bls[2176];   // windowed bias*log2e-24: Bls[i] = b(i + 1920 - q0)
  const int tid = threadIdx.x;
  const int lane = tid & 63, wave = tid >> 6;
  const int l16 = lane & 15, quad = lane >> 4;
  const int bh = blockIdx.y;
  const int b = bh >> 4, h = bh & 15;
  const int q0 = blockIdx.x << 7;
  const int wq = wave << 5;

  const unsigned short* Qp = Q + (size_t)bh * S_LEN * 64;
  const unsigned short* Kp = K + (size_t)bh * S_LEN * 64;
  const unsigned short* Vp = Vt + (size_t)bh * 64 * S_LEN;
  const float* biasg = bias + h * 4095 + (1920 - q0);

  // stage tile 0 + bias window + Q fragments before the first barrier
  STAGE_KV(0, 0);
  for (int i = tid; i < 2175; i += 256)
    Bls[i] = fmaf(biasg[i], 1.44269504f, -24.f);

  bf16x8 qf[2][2];
#pragma unroll
  for (int mi = 0; mi < 2; ++mi)
#pragma unroll
    for (int ks = 0; ks < 2; ++ks)
      qf[mi][ks] = ld_frag(Qp + (size_t)(q0 + wq + mi * 16 + l16) * 64 + ks * 32 + quad * 8);

  float l_run[2][4] = {};
  floatx4 oacc[2][4] = {};

  const int qwb = q0 + wq;                          // wave's first q row
  const int rbase = 127 + l16 - wq - (quad << 2);   // Bls idx base minus kv0, mi, i

  __syncthreads();  // tile 0 staged + bias visible
  const float Bneg = Bls[0], Bpos = Bls[2174];

  for (int kv0 = 0; kv0 < S_LEN; kv0 += 64) {
    const int cur = (kv0 >> 6) & 1;
    if (kv0 + 64 < S_LEN) STAGE_KV(kv0 + 64, cur ^ 1);  // hides under this tile's compute

    // ---- QK^T from swizzled LDS K ----
    floatx4 sac[2][4] = {};
#pragma unroll
    for (int ks = 0; ks < 2; ++ks) {
      bf16x8 kf[4];
#pragma unroll
      for (int ni = 0; ni < 4; ++ni)
        kf[ni] = *(const bf16x8*)&Ks[cur][(ni * 16 + l16) * 64 +
                                          ((((ks << 2) + quad) ^ (l16 & 7)) << 3)];
#pragma unroll
      for (int mi = 0; mi < 2; ++mi)
#pragma unroll
        for (int ni = 0; ni < 4; ++ni)
          sac[mi][ni] = __builtin_amdgcn_mfma_f32_16x16x32_bf16(qf[mi][ks], kf[ni], sac[mi][ni], 0, 0, 0);
    }

    // ---- fixed-max softmax (saturated-bucket fast path) ----
    {
      const int dmin = kv0 - (qwb + 31);
      const int dmax = kv0 + 63 - qwb;
      if (dmin >= 96 || dmax <= -96) {
        const float bc = (dmin >= 96) ? Bpos : Bneg;
#pragma unroll
        for (int mi = 0; mi < 2; ++mi)
#pragma unroll
          for (int i = 0; i < 4; ++i) {
            float sum = 0.f;
#pragma unroll
            for (int ni = 0; ni < 4; ++ni) {
              float e = __builtin_amdgcn_exp2f(fmaf(sac[mi][ni][i], 1.44269504f, bc));
              sac[mi][ni][i] = e; sum += e;
            }
            l_run[mi][i] += sum;
          }
      } else {
#pragma unroll
        for (int mi = 0; mi < 2; ++mi)
#pragma unroll
          for (int i = 0; i < 4; ++i) {
            const int bbase = kv0 + rbase - i - mi * 16;
            float sum = 0.f;
#pragma unroll
            for (int ni = 0; ni < 4; ++ni) {
              float e = __builtin_amdgcn_exp2f(
                  fmaf(sac[mi][ni][i], 1.44269504f, Bls[bbase + ni * 16]));
              sac[mi][ni][i] = e; sum += e;
            }
            l_run[mi][i] += sum;
          }
      }
    }

    // ---- P -> LDS (wave-private, no barrier) ----
#pragma unroll
    for (int mi = 0; mi < 2; ++mi)
#pragma unroll
      for (int ni = 0; ni < 4; ++ni)
#pragma unroll
        for (int i = 0; i < 4; ++i)
          Ps[wave][mi * 16 + quad * 4 + i][ni * 16 + l16] = f2bf(sac[mi][ni][i]);

    // ---- PV from swizzled LDS V ----
#pragma unroll
    for (int ks2 = 0; ks2 < 2; ++ks2) {
      bf16x8 af[2], vf[4];
#pragma unroll
      for (int mi = 0; mi < 2; ++mi)
        af[mi] = *(const bf16x8*)&Ps[wave][mi * 16 + l16][ks2 * 32 + quad * 8];
#pragma unroll
      for (int ni = 0; ni < 4; ++ni)
        vf[ni] = *(const bf16x8*)&Vs[cur][(ni * 16 + l16) * 64 +
                                          ((((ks2 << 2) + quad) ^ (l16 & 7)) << 3)];
#pragma unroll
      for (int mi = 0; mi < 2; ++mi)
#pragma unroll
        for (int ni = 0; ni < 4; ++ni)
          oacc[mi][ni] = __builtin_amdgcn_mfma_f32_16x16x32_bf16(af[mi], vf[ni], oacc[mi][ni], 0, 0, 0);
    }

    __syncthreads();  // next-tile staging drained; everyone done with buf[cur]
  }

  // one-time cross-lane l reduction (columns live on the 16 lanes of each quad)
  float linv[2][4];
#pragma unroll
  for (int mi = 0; mi < 2; ++mi)
#pragma unroll
    for (int i = 0; i < 4; ++i) {
      float ls = l_run[mi][i];
      ls += __shfl_xor(ls, 1);
      ls += __shfl_xor(ls, 2);
      ls += __shfl_xor(ls, 4);
      ls += __shfl_xor(ls, 8);
      linv[mi][i] = 1.f / ls;
    }

#pragma unroll
  for (int mi = 0; mi < 2; ++mi)
#pragma unroll
    for (int ni = 0; ni < 4; ++ni)
#pragma unroll
      for (int i = 0; i < 4; ++i) {
        float v = oacc[mi][ni][i] * linv[mi][i];
        int srow = q0 + wq + mi * 16 + quad * 4 + i;
        ctx[((size_t)(b * 2048 + srow)) * 1024 + h * 64 + ni * 16 + l16] = f2bf(v);
      }
}

extern "C" void kernel_launch(void* const* d_in, const int* in_sizes, int n_in,
                              void* d_out, int out_size, void* d_ws, size_t ws_size,
                              hipStream_t stream) {
  char* ws = (char*)d_ws;
  // R2/R6-proven workspace layout, byte-for-byte.
  unsigned short* Xbf  = (unsigned short*)(ws);                    // 8 MB
  unsigned short* Wcat = (unsigned short*)(ws + 8388608);          // 6 MB (Wq^T|Wk^T|Wv^T)
  unsigned short* Wto  = (unsigned short*)(ws + 14680064);         // 2 MB
  unsigned short* Qb   = (unsigned short*)(ws + 16777216);         // 8 MB  (K at +8MB, Vt at +16MB)
  unsigned short* ctx  = (unsigned short*)(ws + 41943040);         // 8 MB
  float*          bias = (float*)(ws + 50331648);                  // 16*4095*4
  int*            flag = (int*)(ws + 50593792);

  unsigned short* Kb  = Qb + 4194304;
  unsigned short* Vtb = Qb + 8388608;

  detect_k<<<1, 256, 0, stream>>>((const unsigned short*)d_in[0], flag);
  conv_x<<<2048, 256, 0, stream>>>(d_in[0], Xbf, flag, 524288);
  transpose_w<<<dim3(32, 32, 4), dim3(32, 8), 0, stream>>>(
      d_in[1], d_in[2], d_in[3], d_in[4], Wcat, Wto, flag);
  bias_k<<<256, 256, 0, stream>>>(d_in[5], bias, flag);

  // fused QKV GEMM: [4096,1024] @ [3072,1024]^T -> Q|K|Vt (V^T via LDS transpose)
  gemm_bt<<<dim3(24, 32), 256, 0, stream>>>(Xbf, Wcat, Qb, 0, flag);

  // flash attention: double-buffered LDS K/V, KVBLK=64
  attn_k<<<dim3(16, 32), 256, 0, stream>>>(Qb, Kb, Vtb, bias, ctx);

  // out GEMM: [4096,1024] @ [1024,1024]^T, 128x64 tiles
  gemm_out<<<dim3(16, 32), 256, 0, stream>>>(ctx, Wto, d_out, flag);
}